// Round 13
// baseline (3027.744 us; speedup 1.0000x reference)
//
#include <hip/hip_runtime.h>
#include <hip/hip_bf16.h>
#include <math.h>

typedef __bf16 bf16_t;
typedef __attribute__((ext_vector_type(8))) __bf16 bf16x8;
typedef __attribute__((ext_vector_type(4))) __bf16 bf16x4;
typedef __attribute__((ext_vector_type(4))) float f32x4;

#define B_  4
#define L_  1024
#define D_  1024
#define H_  16
#define HD_ 64
#define NL_ 8
#define V_  32000
#define FF_ 4096

// ---------------- embed + sinusoidal PE -> f32 residual ----------------
__global__ __launch_bounds__(256) void embed_kernel(const int* __restrict__ idx,
                                                    const float* __restrict__ emb,
                                                    float* __restrict__ x) {
  int token = blockIdx.x;           // b*L + l
  int l = token & (L_ - 1);
  int id = idx[token];
  const float* erow = emb + (size_t)id * D_;
  float* xrow = x + (size_t)token * D_;
  int d0 = threadIdx.x * 4;
#pragma unroll
  for (int j = 0; j < 4; ++j) {
    int d = d0 + j;
    int i = d >> 1;
    float freq = expf((float)(2 * i) * (-9.210340371976184f / (float)D_));
    float ang = (float)l * freq;
    float pe = (d & 1) ? cosf(ang) : sinf(ang);
    xrow[d] = erow[d] + pe;
  }
}

// ---------------- LayerNorm: f32 in -> bf16 out ----------------
__global__ __launch_bounds__(256) void ln_kernel(const float* __restrict__ x,
                                                 const float* __restrict__ gamma,
                                                 const float* __restrict__ beta,
                                                 bf16_t* __restrict__ out) {
  int row = blockIdx.x;
  int t = threadIdx.x;
  float4 v = ((const float4*)(x + (size_t)row * D_))[t];
  float va[4] = {v.x, v.y, v.z, v.w};
  float s = va[0] + va[1] + va[2] + va[3];
  float ss = va[0]*va[0] + va[1]*va[1] + va[2]*va[2] + va[3]*va[3];
#pragma unroll
  for (int m = 1; m < 64; m <<= 1) {
    s  += __shfl_xor(s, m);
    ss += __shfl_xor(ss, m);
  }
  __shared__ float red[8];
  int wid = t >> 6, lane = t & 63;
  if (lane == 0) { red[wid] = s; red[4 + wid] = ss; }
  __syncthreads();
  s  = red[0] + red[1] + red[2] + red[3];
  ss = red[4] + red[5] + red[6] + red[7];
  float mu  = s * (1.0f / D_);
  float var = fmaxf(ss * (1.0f / D_) - mu * mu, 0.0f);
  float rstd = rsqrtf(var + 1e-5f);
  int d0 = t * 4;
  bf16_t* orow = out + (size_t)row * D_ + d0;
#pragma unroll
  for (int j = 0; j < 4; ++j) {
    int d = d0 + j;
    orow[j] = (bf16_t)((va[j] - mu) * rstd * gamma[d] + beta[d]);
  }
}

// ---- 64x64 transpose tile body: in[k][n] (f32, row stride ldin) -> out[n][k] (bf16) ----
__device__ __forceinline__ void tr64_body(const float* __restrict__ in, bf16_t* __restrict__ out,
                                          int K, int ldin, int n0, int k0) {
  __shared__ bf16_t tile[64][66];
  int tx = threadIdx.x, ty = threadIdx.y;   // 16 x 16
#pragma unroll
  for (int r = 0; r < 4; ++r) {
    int kk = ty + r * 16;
    float4 v = *(const float4*)(in + (size_t)(k0 + kk) * ldin + n0 + tx * 4);
    tile[kk][tx * 4 + 0] = (bf16_t)v.x;
    tile[kk][tx * 4 + 1] = (bf16_t)v.y;
    tile[kk][tx * 4 + 2] = (bf16_t)v.z;
    tile[kk][tx * 4 + 3] = (bf16_t)v.w;
  }
  __syncthreads();
#pragma unroll
  for (int r = 0; r < 4; ++r) {
    int nn = ty + r * 16;
    bf16x4 w;
    w[0] = tile[tx * 4 + 0][nn];
    w[1] = tile[tx * 4 + 1][nn];
    w[2] = tile[tx * 4 + 2][nn];
    w[3] = tile[tx * 4 + 3][nn];
    *(bf16x4*)(out + (size_t)(n0 + nn) * K + k0 + tx * 4) = w;
  }
}

// ------- head-chunk transpose: in[k][base+n] -> out[n][k] -------
__global__ void transpose64_k(const float* __restrict__ in, size_t base,
                              bf16_t* __restrict__ out, int K, int ldin) {
  tr64_body(in + base, out, K, ldin, blockIdx.x * 64, blockIdx.y * 64);
}

// ------- all-weights transpose (nlayers x 3072 tiles of 64x64) -------
// per-layer output layout (elements): qkvT 0 | woT 3145728 | w1T 4194304 | w2T 8388608
__global__ void transpose_all(const float* __restrict__ wq, const float* __restrict__ wk,
                              const float* __restrict__ wv, const float* __restrict__ wo,
                              const float* __restrict__ w1, const float* __restrict__ w2,
                              int lbase, bf16_t* __restrict__ outbase, size_t lstride) {
  int b = blockIdx.x;
  int li = b / 3072, t = b % 3072;
  int l = lbase + li;
  bf16_t* wl = outbase + (size_t)li * lstride;
  const size_t wofD = (size_t)l * D_ * D_;
  const size_t wofF = (size_t)l * D_ * FF_;
  const float* in; bf16_t* out; int K, ldin, x, y;
  if (t < 768) {
    int z = t >> 8, tt = t & 255;
    in = (z == 0 ? wq : z == 1 ? wk : wv) + wofD;
    out = wl + (size_t)z * D_ * D_;
    K = D_; ldin = D_; x = tt & 15; y = tt >> 4;
  } else if (t < 1024) {
    int tt = t - 768;
    in = wo + wofD; out = wl + 3145728;
    K = D_; ldin = D_; x = tt & 15; y = tt >> 4;
  } else if (t < 2048) {
    int tt = t - 1024;
    in = w1 + wofF; out = wl + 4194304;
    K = D_; ldin = FF_; x = tt & 63; y = tt >> 6;
  } else {
    int tt = t - 2048;
    in = w2 + wofF; out = wl + 8388608;
    K = FF_; ldin = D_; x = tt & 15; y = tt >> 4;
  }
  tr64_body(in, out, K, ldin, x * 64, y * 64);
}

// ---------------- async global->LDS helper ----------------
__device__ __forceinline__ void gload_lds16(const bf16_t* g, bf16_t* lds) {
  __builtin_amdgcn_global_load_lds(
      (const __attribute__((address_space(1))) void*)g,
      (__attribute__((address_space(3))) void*)(void*)lds,
      16, 0, 0);
}

// ---- common bijective XCD + grouped-raster block remap (G=8 bm rows/group) ----
__device__ __forceinline__ void remap_block(int& bn, int& bm) {
  const int gx = gridDim.x, gy = gridDim.y;
  int lin = blockIdx.y * gx + blockIdx.x;
  int nwg = gx * gy;
  int q8 = nwg >> 3, r8 = nwg & 7;
  int xcd = lin & 7, pos = lin >> 3;
  int wg = (xcd < r8 ? xcd * (q8 + 1) : r8 * (q8 + 1) + (xcd - r8) * q8) + pos;
  if ((gy & 7) == 0) {
    int per = gx << 3;
    int grp = wg / per, win = wg % per;
    bm = (grp << 3) + (win & 7);
    bn = win >> 3;
  } else { bn = wg % gx; bm = wg / gx; }
}

// ---------------- 128x128 GEMM (m97 structure) with split-K over blockIdx.z ----------------
// EPI: 1 = atomicAdd resid; 3 = atomicAdd resid (+bias on split 0)
template <int EPI>
__global__ __launch_bounds__(256) void gemm_bt_kernel(
    const bf16_t* __restrict__ A, const bf16_t* __restrict__ Bt,
    bf16_t* __restrict__ outb, float* __restrict__ outf,
    const float* __restrict__ bias, int M, int Nst, int K, int col0) {
  int bn, bm; remap_block(bn, bm);
  const int kz = blockIdx.z, KS = gridDim.z;
  const int Kc = K / KS;
  const int kbeg = kz * Kc, kend = kbeg + Kc;
  const int tid = threadIdx.x, wid = tid >> 6, lane = tid & 63;
  const int wm = wid >> 1, wn = wid & 1;
  const int l15 = lane & 15, l4 = lane >> 4;

  __shared__ __align__(16) bf16_t As[128 * 32];
  __shared__ __align__(16) bf16_t Bs[128 * 32];

  f32x4 acc[4][4] = {};

  const bf16_t* Ablk = A  + (size_t)(bm * 128) * K;
  const bf16_t* Bblk = Bt + (size_t)(bn * 128) * K;
  const int srow = lane >> 2;
  const int skof = (lane & 3) * 8;

  for (int k0 = kbeg; k0 < kend; k0 += 32) {
#pragma unroll
    for (int c = 0; c < 2; ++c) {
      int chunk = wid * 2 + c;
      int row = chunk * 16 + srow;
      gload_lds16(Ablk + (size_t)row * K + k0 + skof, As + chunk * 512);
      gload_lds16(Bblk + (size_t)row * K + k0 + skof, Bs + chunk * 512);
    }
    __syncthreads();

    bf16x8 af[4], bfv[4];
#pragma unroll
    for (int i = 0; i < 4; ++i)
      af[i] = *(const bf16x8*)(As + (wm * 64 + i * 16 + l15) * 32 + l4 * 8);
#pragma unroll
    for (int j = 0; j < 4; ++j)
      bfv[j] = *(const bf16x8*)(Bs + (wn * 64 + j * 16 + l15) * 32 + l4 * 8);
#pragma unroll
    for (int i = 0; i < 4; ++i)
#pragma unroll
      for (int j = 0; j < 4; ++j)
        acc[i][j] = __builtin_amdgcn_mfma_f32_16x16x32_bf16(af[i], bfv[j], acc[i][j], 0, 0, 0);
    __syncthreads();
  }

  const int row_base = bm * 128 + wm * 64;
  const int col_base = col0 + bn * 128 + wn * 64 + l15;
#pragma unroll
  for (int i = 0; i < 4; ++i) {
#pragma unroll
    for (int j = 0; j < 4; ++j) {
      int col = col_base + j * 16;
#pragma unroll
      for (int r = 0; r < 4; ++r) {
        int row = row_base + i * 16 + l4 * 4 + r;
        float val = acc[i][j][r];
        if (EPI == 3 && kz == 0) val += bias[col];
        atomicAdd(&outf[(size_t)row * Nst + col], val);
      }
    }
  }
}

// ------- 256x256 8-wave GEMM, BK=64, 8-phase schedule, race-free stage map -------
// (verified round 11) EPI: 2 = +bias,gelu,bf16; 4 = f32; 5 = QKV split
template <int EPI>
__global__ __launch_bounds__(512, 2) void gemm256_kernel(
    const bf16_t* __restrict__ A, const bf16_t* __restrict__ Bt,
    bf16_t* __restrict__ outb, float* __restrict__ outf,
    const float* __restrict__ bias, int M, int Nst, int K, int col0) {
  int bn, bm; remap_block(bn, bm);
  const int tid = threadIdx.x, wid = tid >> 6, lane = tid & 63;
  const int wm = wid >> 2, wn = wid & 3;          // 2 x 4 waves
  const int l15 = lane & 15, l4 = lane >> 4;

  __shared__ __align__(16) bf16_t smem[65536];

  f32x4 acc[8][4] = {};

  const bf16_t* Ab = A  + (size_t)(bm * 256) * K;
  const bf16_t* Bb = Bt + (size_t)(bn * 256) * K;
  const int NT = K >> 6;

  const int srow = tid >> 3;
  const int sx8  = tid & 7;
  const int xrd  = l15 & 7;

  auto stage_rows = [&](int t, int mat, int R) {
    const bf16_t* g = mat ? Bb : Ab;
    bf16_t* l = smem + (t & 1) * 32768 + mat * 16384 + R * 64;
    int row = R + srow;
    int gs  = sx8 ^ (row & 7);
    gload_lds16(g + (size_t)row * K + t * 64 + gs * 8, l + wid * 512);
  };
  auto stA_SP0 = [&](int t) { stage_rows(t, 0, 0);   stage_rows(t, 0, 128); };
  auto stA_SP1 = [&](int t) { stage_rows(t, 0, 64);  stage_rows(t, 0, 192); };
  auto stB_H0  = [&](int t) { stage_rows(t, 1, 0);   stage_rows(t, 1, 64);  };
  auto stB_H1  = [&](int t) { stage_rows(t, 1, 128); stage_rows(t, 1, 192); };

  stA_SP0(0); stB_H0(0); stA_SP1(0); stB_H1(0);
  stA_SP0(1); stB_H0(1); stA_SP1(1);
  asm volatile("s_waitcnt vmcnt(6)" ::: "memory");
  __builtin_amdgcn_s_barrier();

  bf16x8 af[4][2], bfr[4][2];

  auto rdB = [&](const bf16_t* sB, int nh) {
#pragma unroll
    for (int n = 0; n < 2; ++n)
#pragma unroll
      for (int ks = 0; ks < 2; ++ks)
        bfr[nh * 2 + n][ks] = *(const bf16x8*)(sB + (wn * 64 + (nh * 2 + n) * 16 + l15) * 64
                                                  + ((ks * 4 + l4) ^ xrd) * 8);
  };
  auto rdA = [&](const bf16_t* sA, int mh) {
#pragma unroll
    for (int m = 0; m < 4; ++m)
#pragma unroll
      for (int ks = 0; ks < 2; ++ks)
        af[m][ks] = *(const bf16x8*)(sA + (wm * 128 + mh * 64 + m * 16 + l15) * 64
                                        + ((ks * 4 + l4) ^ xrd) * 8);
  };
  auto mma = [&](int mh, int nh) {
    asm volatile("s_waitcnt lgkmcnt(0)" ::: "memory");
    __builtin_amdgcn_sched_barrier(0);
    __builtin_amdgcn_s_setprio(1);
#pragma unroll
    for (int m = 0; m < 4; ++m)
#pragma unroll
      for (int n = 0; n < 2; ++n)
#pragma unroll
        for (int ks = 0; ks < 2; ++ks)
          acc[mh * 4 + m][nh * 2 + n] = __builtin_amdgcn_mfma_f32_16x16x32_bf16(
              af[m][ks], bfr[nh * 2 + n][ks], acc[mh * 4 + m][nh * 2 + n], 0, 0, 0);
    __builtin_amdgcn_s_setprio(0);
  };

  const int NI = NT >> 1;
  for (int it = 0; it < NI; ++it) {
    const int T0 = 2 * it, T1 = 2 * it + 1;
    const bool pre = (it + 1 < NI);
    const bf16_t* sA0 = smem;
    const bf16_t* sB0 = smem + 16384;
    const bf16_t* sA1 = smem + 32768;
    const bf16_t* sB1 = smem + 49152;

    rdB(sB0, 0); rdA(sA0, 0);
    stB_H1(T1);
    __builtin_amdgcn_s_barrier();
    mma(0, 0);
    __builtin_amdgcn_s_barrier();
    rdB(sB0, 1);
    if (pre) stA_SP0(T0 + 2);
    __builtin_amdgcn_s_barrier();
    mma(0, 1);
    __builtin_amdgcn_s_barrier();
    rdA(sA0, 1);
    if (pre) stB_H0(T0 + 2);
    __builtin_amdgcn_s_barrier();
    mma(1, 0);
    __builtin_amdgcn_s_barrier();
    if (pre) stA_SP1(T0 + 2);
    __builtin_amdgcn_s_barrier();
    mma(1, 1);
    if (pre) { asm volatile("s_waitcnt vmcnt(6)" ::: "memory"); }
    else     { asm volatile("s_waitcnt vmcnt(0)" ::: "memory"); }
    __builtin_amdgcn_s_barrier();

    rdB(sB1, 0); rdA(sA1, 0);
    if (pre) stB_H1(T0 + 2);
    __builtin_amdgcn_s_barrier();
    mma(0, 0);
    __builtin_amdgcn_s_barrier();
    rdB(sB1, 1);
    if (pre) stA_SP0(T1 + 2);
    __builtin_amdgcn_s_barrier();
    mma(0, 1);
    __builtin_amdgcn_s_barrier();
    rdA(sA1, 1);
    if (pre) stB_H0(T1 + 2);
    __builtin_amdgcn_s_barrier();
    mma(1, 0);
    __builtin_amdgcn_s_barrier();
    if (pre) stA_SP1(T1 + 2);
    __builtin_amdgcn_s_barrier();
    mma(1, 1);
    if (pre) { asm volatile("s_waitcnt vmcnt(6)" ::: "memory"); }
    __builtin_amdgcn_s_barrier();
  }

  const int row_base = bm * 256 + wm * 128;
#pragma unroll
  for (int m = 0; m < 8; ++m) {
#pragma unroll
    for (int n = 0; n < 4; ++n) {
      int colg = bn * 256 + wn * 64 + n * 16 + l15;
#pragma unroll
      for (int r = 0; r < 4; ++r) {
        int row = row_base + m * 16 + l4 * 4 + r;
        float val = acc[m][n][r];
        if (EPI == 4) {
          outf[(size_t)row * Nst + col0 + colg] = val;
        } else if (EPI == 2) {
          int col = col0 + colg;
          float v2 = val + bias[col];
          v2 = 0.5f * v2 * (1.0f + erff(v2 * 0.7071067811865475f));
          outb[(size_t)row * Nst + col] = (bf16_t)v2;
        } else {
          int buf = colg >> 10;
          int lc  = colg & 1023;
          (outb + (size_t)buf * 4194304)[(size_t)row * 1024 + lc] = (bf16_t)val;
        }
      }
    }
  }
}

// ---------------- flash attention (causal), 1 block = (b, h, 64 q-rows) ----------------
__global__ __launch_bounds__(256) void attn_kernel(
    const bf16_t* __restrict__ q, const bf16_t* __restrict__ k,
    const bf16_t* __restrict__ v, bf16_t* __restrict__ y) {
  int bid = blockIdx.x;
  int qt = bid & 15;
  int h  = (bid >> 4) & (H_ - 1);
  int b  = bid >> 8;
  int tid = threadIdx.x, wid = tid >> 6, lane = tid & 63;
  int l15 = lane & 15, l4 = lane >> 4;

  __shared__ __align__(16) bf16_t Ks[64 * 72];
  __shared__ __align__(16) bf16_t Vs[64 * 72];
  __shared__ __align__(16) bf16_t Ps[4][16 * 72];

  const int qrow0 = qt * 64 + wid * 16;
  const size_t bh = ((size_t)b * L_ * H_ + h) * HD_;

  bf16x8 qf[2];
#pragma unroll
  for (int c = 0; c < 2; ++c)
    qf[c] = *(const bf16x8*)(q + bh + (size_t)(qrow0 + l15) * (H_ * HD_) + c * 32 + l4 * 8);

  float m_r[4] = {-INFINITY, -INFINITY, -INFINITY, -INFINITY};
  float l_r[4] = {0.f, 0.f, 0.f, 0.f};
  f32x4 oacc[4] = {};

  for (int kt = 0; kt <= qt; ++kt) {
    __syncthreads();
    int kbase = kt * 64;
#pragma unroll
    for (int s = 0; s < 2; ++s) {
      int seg = s * 256 + tid;
      int j = seg >> 3;
      int dof = (seg & 7) * 8;
      const size_t src = bh + (size_t)(kbase + j) * (H_ * HD_) + dof;
      *(bf16x8*)(Ks + j * 72 + dof) = *(const bf16x8*)(k + src);
      bf16x8 vv = *(const bf16x8*)(v + src);
      int colb = (j + dof) & 63;
#pragma unroll
      for (int jj = 0; jj < 8; ++jj) Vs[(dof + jj) * 72 + colb] = vv[jj];
    }
    __syncthreads();

    f32x4 sacc[4] = {};
#pragma unroll
    for (int c = 0; c < 2; ++c) {
#pragma unroll
      for (int t = 0; t < 4; ++t) {
        bf16x8 kf = *(const bf16x8*)(Ks + (t * 16 + l15) * 72 + c * 32 + l4 * 8);
        sacc[t] = __builtin_amdgcn_mfma_f32_16x16x32_bf16(qf[c], kf, sacc[t], 0, 0, 0);
      }
    }

    float tmax[4] = {-INFINITY, -INFINITY, -INFINITY, -INFINITY};
#pragma unroll
    for (int t = 0; t < 4; ++t) {
#pragma unroll
      for (int r = 0; r < 4; ++r) {
        float sv = sacc[t][r] * 0.125f;
        int kj = kbase + t * 16 + l15;
        int qi = qrow0 + l4 * 4 + r;
        if (kj > qi) sv = -INFINITY;
        sacc[t][r] = sv;
        tmax[r] = fmaxf(tmax[r], sv);
      }
    }
#pragma unroll
    for (int r = 0; r < 4; ++r) {
#pragma unroll
      for (int md = 1; md < 16; md <<= 1)
        tmax[r] = fmaxf(tmax[r], __shfl_xor(tmax[r], md));
    }
    float alpha[4], tsum[4];
#pragma unroll
    for (int r = 0; r < 4; ++r) {
      float mn = fmaxf(m_r[r], tmax[r]);
      alpha[r] = expf(m_r[r] - mn);
      m_r[r] = mn;
      tsum[r] = 0.f;
    }
#pragma unroll
    for (int t = 0; t < 4; ++t) {
#pragma unroll
      for (int r = 0; r < 4; ++r) {
        float p = expf(sacc[t][r] - m_r[r]);
        tsum[r] += p;
        Ps[wid][(l4 * 4 + r) * 72 + t * 16 + l15] = (bf16_t)p;
      }
    }
#pragma unroll
    for (int r = 0; r < 4; ++r) {
#pragma unroll
      for (int md = 1; md < 16; md <<= 1)
        tsum[r] += __shfl_xor(tsum[r], md);
      l_r[r] = l_r[r] * alpha[r] + tsum[r];
    }
#pragma unroll
    for (int t = 0; t < 4; ++t)
#pragma unroll
      for (int r = 0; r < 4; ++r)
        oacc[t][r] *= alpha[r];

#pragma unroll
    for (int c = 0; c < 2; ++c) {
      bf16x8 pf = *(const bf16x8*)(&Ps[wid][l15 * 72 + c * 32 + l4 * 8]);
#pragma unroll
      for (int t = 0; t < 4; ++t) {
        int d = t * 16 + l15;
        int jb = c * 32 + l4 * 8;
        bf16x8 vf = *(const bf16x8*)(Vs + d * 72 + ((jb + (d & 56)) & 63));
        oacc[t] = __builtin_amdgcn_mfma_f32_16x16x32_bf16(pf, vf, oacc[t], 0, 0, 0);
      }
    }
  }

#pragma unroll
  for (int t = 0; t < 4; ++t) {
#pragma unroll
    for (int r = 0; r < 4; ++r) {
      int row = qrow0 + l4 * 4 + r;
      int d = t * 16 + l15;
      y[bh + (size_t)row * (H_ * HD_) + d] = (bf16_t)(oacc[t][r] / l_r[r]);
    }
  }
}

// ---------------- host launcher ----------------
extern "C" void kernel_launch(void* const* d_in, const int* in_sizes, int n_in,
                              void* d_out, int out_size, void* d_ws, size_t ws_size,
                              hipStream_t stream) {
  (void)in_sizes; (void)n_in; (void)out_size;
  const int*   idx   = (const int*)d_in[0];
  const float* emb   = (const float*)d_in[1];
  const float* ln1_s = (const float*)d_in[2];
  const float* ln1_b = (const float*)d_in[3];
  const float* wq    = (const float*)d_in[4];
  const float* wk    = (const float*)d_in[5];
  const float* wv    = (const float*)d_in[6];
  const float* wo    = (const float*)d_in[7];
  const float* ln2_s = (const float*)d_in[8];
  const float* ln2_b = (const float*)d_in[9];
  const float* w1    = (const float*)d_in[10];
  const float* b1    = (const float*)d_in[11];
  const float* w2    = (const float*)d_in[12];
  const float* b2    = (const float*)d_in[13];
  const float* lnf_s = (const float*)d_in[14];
  const float* lnf_b = (const float*)d_in[15];
  const float* headw = (const float*)d_in[16];
  float* out = (float*)d_out;

  char* ws = (char*)d_ws;
  const size_t XO  = 0;
  const size_t HBO = XO  + 16777216;     // f32 residual 4096x1024
  const size_t QBO = HBO + 8388608;      // bf16 4096x1024 each; Q,K,V contiguous
  const size_t KBO = QBO + 8388608;
  const size_t VBO = KBO + 8388608;
  const size_t YBO = VBO + 8388608;
  const size_t GBO = QBO;                // FFN intermediate overlaps Q/K/V/Y
  const size_t WTO = YBO + 8388608;      // weight-transpose staging region
  const size_t LBYTES = 25165824;        // 24 MB per layer (qkv 6 + wo 2 + w1 8 + w2 8)
  const size_t LELEMS = LBYTES / 2;      // 12582912 elements
  const bool prepass = ws_size >= WTO + (size_t)NL_ * LBYTES;

  float*  X   = (float*)(ws + XO);
  bf16_t* Hb  = (bf16_t*)(ws + HBO);
  bf16_t* Qb  = (bf16_t*)(ws + QBO);
  bf16_t* Kb  = (bf16_t*)(ws + KBO);
  bf16_t* Vb  = (bf16_t*)(ws + VBO);
  bf16_t* Yb  = (bf16_t*)(ws + YBO);
  bf16_t* Gb  = (bf16_t*)(ws + GBO);
  bf16_t* Wbase = (bf16_t*)(ws + WTO);
  bf16_t* WT    = (bf16_t*)(ws + WTO);   // head transpose reuses region after layers

  const int M = B_ * L_;                 // 4096
  const dim3 tb16(16, 16);

  embed_kernel<<<M, 256, 0, stream>>>(idx, emb, X);

  if (prepass)
    transpose_all<<<NL_ * 3072, tb16, 0, stream>>>(wq, wk, wv, wo, w1, w2, 0, Wbase, LELEMS);

  for (int l = 0; l < NL_; ++l) {
    bf16_t* wl = prepass ? (Wbase + (size_t)l * LELEMS) : Wbase;
    bf16_t* qkvT = wl;
    bf16_t* woT  = wl + 3145728;
    bf16_t* w1T  = wl + 4194304;
    bf16_t* w2T  = wl + 8388608;

    ln_kernel<<<M, 256, 0, stream>>>(X, ln1_s + (size_t)l * D_, ln1_b + (size_t)l * D_, Hb);

    if (!prepass)
      transpose_all<<<3072, tb16, 0, stream>>>(wq, wk, wv, wo, w1, w2, l, Wbase, 0);

    gemm256_kernel<5><<<dim3(3*D_/256, M/256), 512, 0, stream>>>(Hb, qkvT, Qb, nullptr, nullptr, M, D_, D_, 0);

    attn_kernel<<<B_ * H_ * (L_/64), 256, 0, stream>>>(Qb, Kb, Vb, Yb);

    gemm_bt_kernel<1><<<dim3(D_/128, M/128, 2), 256, 0, stream>>>(Yb, woT, nullptr, X, nullptr, M, D_, D_, 0);

    ln_kernel<<<M, 256, 0, stream>>>(X, ln2_s + (size_t)l * D_, ln2_b + (size_t)l * D_, Hb);

    gemm256_kernel<2><<<dim3(FF_/256, M/256), 512, 0, stream>>>(Hb, w1T, Gb, nullptr, b1 + (size_t)l * FF_, M, FF_, D_, 0);

    gemm_bt_kernel<3><<<dim3(D_/128, M/128, 4), 256, 0, stream>>>(Gb, w2T, nullptr, X, b2 + (size_t)l * D_, M, D_, FF_, 0);
  }

  ln_kernel<<<M, 256, 0, stream>>>(X, lnf_s, lnf_b, Hb);

  // head GEMM -> f32 logits; chunked at 16384 cols (visibility: exposes per-layer
  // kernels in rocprof top-5). 32000 = 16384 + 15616, both /256 and /64.
  size_t avail = (ws_size > WTO) ? (ws_size - WTO) : 0;
  long long maxcols = (long long)(avail / ((size_t)D_ * 2));
  int chunk = (int)((maxcols / 256) * 256);
  if (chunk > 16384) chunk = 16384;
  if (chunk < 256) chunk = 256;
  for (int n0 = 0; n0 < V_; n0 += chunk) {
    int nc = (V_ - n0 < chunk) ? (V_ - n0) : chunk;
    transpose64_k<<<dim3(nc/64, D_/64), tb16, 0, stream>>>(headw, (size_t)n0, WT, D_, V_);
    gemm256_kernel<4><<<dim3(nc/256, M/256), 512, 0, stream>>>(Hb, WT, nullptr, out, nullptr, M, V_, D_, n0);
  }
}

// Round 14
// 2952.559 us; speedup vs baseline: 1.0255x; 1.0255x over previous
//
#include <hip/hip_runtime.h>
#include <hip/hip_bf16.h>
#include <math.h>

typedef __bf16 bf16_t;
typedef __attribute__((ext_vector_type(8))) __bf16 bf16x8;
typedef __attribute__((ext_vector_type(4))) __bf16 bf16x4;
typedef __attribute__((ext_vector_type(4))) float f32x4;

#define B_  4
#define L_  1024
#define D_  1024
#define H_  16
#define HD_ 64
#define NL_ 8
#define V_  32000
#define FF_ 4096

// ---------------- embed + sinusoidal PE -> f32 residual ----------------
__global__ __launch_bounds__(256) void embed_kernel(const int* __restrict__ idx,
                                                    const float* __restrict__ emb,
                                                    float* __restrict__ x) {
  int token = blockIdx.x;           // b*L + l
  int l = token & (L_ - 1);
  int id = idx[token];
  const float* erow = emb + (size_t)id * D_;
  float* xrow = x + (size_t)token * D_;
  int d0 = threadIdx.x * 4;
#pragma unroll
  for (int j = 0; j < 4; ++j) {
    int d = d0 + j;
    int i = d >> 1;
    float freq = expf((float)(2 * i) * (-9.210340371976184f / (float)D_));
    float ang = (float)l * freq;
    float pe = (d & 1) ? cosf(ang) : sinf(ang);
    xrow[d] = erow[d] + pe;
  }
}

// ---------------- LayerNorm: f32 in -> bf16 out ----------------
__global__ __launch_bounds__(256) void ln_kernel(const float* __restrict__ x,
                                                 const float* __restrict__ gamma,
                                                 const float* __restrict__ beta,
                                                 bf16_t* __restrict__ out) {
  int row = blockIdx.x;
  int t = threadIdx.x;
  float4 v = ((const float4*)(x + (size_t)row * D_))[t];
  float va[4] = {v.x, v.y, v.z, v.w};
  float s = va[0] + va[1] + va[2] + va[3];
  float ss = va[0]*va[0] + va[1]*va[1] + va[2]*va[2] + va[3]*va[3];
#pragma unroll
  for (int m = 1; m < 64; m <<= 1) {
    s  += __shfl_xor(s, m);
    ss += __shfl_xor(ss, m);
  }
  __shared__ float red[8];
  int wid = t >> 6, lane = t & 63;
  if (lane == 0) { red[wid] = s; red[4 + wid] = ss; }
  __syncthreads();
  s  = red[0] + red[1] + red[2] + red[3];
  ss = red[4] + red[5] + red[6] + red[7];
  float mu  = s * (1.0f / D_);
  float var = fmaxf(ss * (1.0f / D_) - mu * mu, 0.0f);
  float rstd = rsqrtf(var + 1e-5f);
  int d0 = t * 4;
  bf16_t* orow = out + (size_t)row * D_ + d0;
#pragma unroll
  for (int j = 0; j < 4; ++j) {
    int d = d0 + j;
    orow[j] = (bf16_t)((va[j] - mu) * rstd * gamma[d] + beta[d]);
  }
}

// ---- 64x64 transpose tile body: in[k][n] (f32, row stride ldin) -> out[n][k] (bf16) ----
__device__ __forceinline__ void tr64_body(const float* __restrict__ in, bf16_t* __restrict__ out,
                                          int K, int ldin, int n0, int k0) {
  __shared__ bf16_t tile[64][66];
  int tx = threadIdx.x, ty = threadIdx.y;   // 16 x 16
#pragma unroll
  for (int r = 0; r < 4; ++r) {
    int kk = ty + r * 16;
    float4 v = *(const float4*)(in + (size_t)(k0 + kk) * ldin + n0 + tx * 4);
    tile[kk][tx * 4 + 0] = (bf16_t)v.x;
    tile[kk][tx * 4 + 1] = (bf16_t)v.y;
    tile[kk][tx * 4 + 2] = (bf16_t)v.z;
    tile[kk][tx * 4 + 3] = (bf16_t)v.w;
  }
  __syncthreads();
#pragma unroll
  for (int r = 0; r < 4; ++r) {
    int nn = ty + r * 16;
    bf16x4 w;
    w[0] = tile[tx * 4 + 0][nn];
    w[1] = tile[tx * 4 + 1][nn];
    w[2] = tile[tx * 4 + 2][nn];
    w[3] = tile[tx * 4 + 3][nn];
    *(bf16x4*)(out + (size_t)(n0 + nn) * K + k0 + tx * 4) = w;
  }
}

// ------- head-chunk transpose: in[k][base+n] -> out[n][k] -------
__global__ void transpose64_k(const float* __restrict__ in, size_t base,
                              bf16_t* __restrict__ out, int K, int ldin) {
  tr64_body(in + base, out, K, ldin, blockIdx.x * 64, blockIdx.y * 64);
}

// ------- all-weights transpose (nlayers x 3072 tiles of 64x64) -------
// per-layer output layout (elements): qkvT 0 | woT 3145728 | w1T 4194304 | w2T 8388608
__global__ void transpose_all(const float* __restrict__ wq, const float* __restrict__ wk,
                              const float* __restrict__ wv, const float* __restrict__ wo,
                              const float* __restrict__ w1, const float* __restrict__ w2,
                              int lbase, bf16_t* __restrict__ outbase, size_t lstride) {
  int b = blockIdx.x;
  int li = b / 3072, t = b % 3072;
  int l = lbase + li;
  bf16_t* wl = outbase + (size_t)li * lstride;
  const size_t wofD = (size_t)l * D_ * D_;
  const size_t wofF = (size_t)l * D_ * FF_;
  const float* in; bf16_t* out; int K, ldin, x, y;
  if (t < 768) {
    int z = t >> 8, tt = t & 255;
    in = (z == 0 ? wq : z == 1 ? wk : wv) + wofD;
    out = wl + (size_t)z * D_ * D_;
    K = D_; ldin = D_; x = tt & 15; y = tt >> 4;
  } else if (t < 1024) {
    int tt = t - 768;
    in = wo + wofD; out = wl + 3145728;
    K = D_; ldin = D_; x = tt & 15; y = tt >> 4;
  } else if (t < 2048) {
    int tt = t - 1024;
    in = w1 + wofF; out = wl + 4194304;
    K = D_; ldin = FF_; x = tt & 63; y = tt >> 6;
  } else {
    int tt = t - 2048;
    in = w2 + wofF; out = wl + 8388608;
    K = FF_; ldin = D_; x = tt & 15; y = tt >> 4;
  }
  tr64_body(in, out, K, ldin, x * 64, y * 64);
}

// ---------------- async global->LDS helper ----------------
__device__ __forceinline__ void gload_lds16(const bf16_t* g, bf16_t* lds) {
  __builtin_amdgcn_global_load_lds(
      (const __attribute__((address_space(1))) void*)g,
      (__attribute__((address_space(3))) void*)(void*)lds,
      16, 0, 0);
}

// ---- common bijective XCD + grouped-raster block remap (G=8 bm rows/group) ----
__device__ __forceinline__ void remap_block(int& bn, int& bm) {
  const int gx = gridDim.x, gy = gridDim.y;
  int lin = blockIdx.y * gx + blockIdx.x;
  int nwg = gx * gy;
  int q8 = nwg >> 3, r8 = nwg & 7;
  int xcd = lin & 7, pos = lin >> 3;
  int wg = (xcd < r8 ? xcd * (q8 + 1) : r8 * (q8 + 1) + (xcd - r8) * q8) + pos;
  if ((gy & 7) == 0) {
    int per = gx << 3;
    int grp = wg / per, win = wg % per;
    bm = (grp << 3) + (win & 7);
    bn = win >> 3;
  } else { bn = wg % gx; bm = wg / gx; }
}

// ---------------- 128x128 GEMM (m97 structure) with split-K over blockIdx.z ----------------
// EPI: 1 = atomicAdd resid; 3 = atomicAdd resid (+bias on split 0)
template <int EPI>
__global__ __launch_bounds__(256) void gemm_bt_kernel(
    const bf16_t* __restrict__ A, const bf16_t* __restrict__ Bt,
    bf16_t* __restrict__ outb, float* __restrict__ outf,
    const float* __restrict__ bias, int M, int Nst, int K, int col0) {
  int bn, bm; remap_block(bn, bm);
  const int kz = blockIdx.z, KS = gridDim.z;
  const int Kc = K / KS;
  const int kbeg = kz * Kc, kend = kbeg + Kc;
  const int tid = threadIdx.x, wid = tid >> 6, lane = tid & 63;
  const int wm = wid >> 1, wn = wid & 1;
  const int l15 = lane & 15, l4 = lane >> 4;

  __shared__ __align__(16) bf16_t As[128 * 32];
  __shared__ __align__(16) bf16_t Bs[128 * 32];

  f32x4 acc[4][4] = {};

  const bf16_t* Ablk = A  + (size_t)(bm * 128) * K;
  const bf16_t* Bblk = Bt + (size_t)(bn * 128) * K;
  const int srow = lane >> 2;
  const int skof = (lane & 3) * 8;

  for (int k0 = kbeg; k0 < kend; k0 += 32) {
#pragma unroll
    for (int c = 0; c < 2; ++c) {
      int chunk = wid * 2 + c;
      int row = chunk * 16 + srow;
      gload_lds16(Ablk + (size_t)row * K + k0 + skof, As + chunk * 512);
      gload_lds16(Bblk + (size_t)row * K + k0 + skof, Bs + chunk * 512);
    }
    __syncthreads();

    bf16x8 af[4], bfv[4];
#pragma unroll
    for (int i = 0; i < 4; ++i)
      af[i] = *(const bf16x8*)(As + (wm * 64 + i * 16 + l15) * 32 + l4 * 8);
#pragma unroll
    for (int j = 0; j < 4; ++j)
      bfv[j] = *(const bf16x8*)(Bs + (wn * 64 + j * 16 + l15) * 32 + l4 * 8);
#pragma unroll
    for (int i = 0; i < 4; ++i)
#pragma unroll
      for (int j = 0; j < 4; ++j)
        acc[i][j] = __builtin_amdgcn_mfma_f32_16x16x32_bf16(af[i], bfv[j], acc[i][j], 0, 0, 0);
    __syncthreads();
  }

  const int row_base = bm * 128 + wm * 64;
  const int col_base = col0 + bn * 128 + wn * 64 + l15;
#pragma unroll
  for (int i = 0; i < 4; ++i) {
#pragma unroll
    for (int j = 0; j < 4; ++j) {
      int col = col_base + j * 16;
#pragma unroll
      for (int r = 0; r < 4; ++r) {
        int row = row_base + i * 16 + l4 * 4 + r;
        float val = acc[i][j][r];
        if (EPI == 3 && kz == 0) val += bias[col];
        atomicAdd(&outf[(size_t)row * Nst + col], val);
      }
    }
  }
}

// ------- 256x256 8-wave GEMM, BK=64, 8-phase schedule, race-free stage map -------
// (verified round 11) EPI: 2 = +bias,gelu,bf16; 4 = f32; 5 = QKV split
template <int EPI>
__global__ __launch_bounds__(512, 2) void gemm256_kernel(
    const bf16_t* __restrict__ A, const bf16_t* __restrict__ Bt,
    bf16_t* __restrict__ outb, float* __restrict__ outf,
    const float* __restrict__ bias, int M, int Nst, int K, int col0) {
  int bn, bm; remap_block(bn, bm);
  const int tid = threadIdx.x, wid = tid >> 6, lane = tid & 63;
  const int wm = wid >> 2, wn = wid & 3;          // 2 x 4 waves
  const int l15 = lane & 15, l4 = lane >> 4;

  __shared__ __align__(16) bf16_t smem[65536];

  f32x4 acc[8][4] = {};

  const bf16_t* Ab = A  + (size_t)(bm * 256) * K;
  const bf16_t* Bb = Bt + (size_t)(bn * 256) * K;
  const int NT = K >> 6;

  const int srow = tid >> 3;
  const int sx8  = tid & 7;
  const int xrd  = l15 & 7;

  auto stage_rows = [&](int t, int mat, int R) {
    const bf16_t* g = mat ? Bb : Ab;
    bf16_t* l = smem + (t & 1) * 32768 + mat * 16384 + R * 64;
    int row = R + srow;
    int gs  = sx8 ^ (row & 7);
    gload_lds16(g + (size_t)row * K + t * 64 + gs * 8, l + wid * 512);
  };
  auto stA_SP0 = [&](int t) { stage_rows(t, 0, 0);   stage_rows(t, 0, 128); };
  auto stA_SP1 = [&](int t) { stage_rows(t, 0, 64);  stage_rows(t, 0, 192); };
  auto stB_H0  = [&](int t) { stage_rows(t, 1, 0);   stage_rows(t, 1, 64);  };
  auto stB_H1  = [&](int t) { stage_rows(t, 1, 128); stage_rows(t, 1, 192); };

  stA_SP0(0); stB_H0(0); stA_SP1(0); stB_H1(0);
  stA_SP0(1); stB_H0(1); stA_SP1(1);
  asm volatile("s_waitcnt vmcnt(6)" ::: "memory");
  __builtin_amdgcn_s_barrier();

  bf16x8 af[4][2], bfr[4][2];

  auto rdB = [&](const bf16_t* sB, int nh) {
#pragma unroll
    for (int n = 0; n < 2; ++n)
#pragma unroll
      for (int ks = 0; ks < 2; ++ks)
        bfr[nh * 2 + n][ks] = *(const bf16x8*)(sB + (wn * 64 + (nh * 2 + n) * 16 + l15) * 64
                                                  + ((ks * 4 + l4) ^ xrd) * 8);
  };
  auto rdA = [&](const bf16_t* sA, int mh) {
#pragma unroll
    for (int m = 0; m < 4; ++m)
#pragma unroll
      for (int ks = 0; ks < 2; ++ks)
        af[m][ks] = *(const bf16x8*)(sA + (wm * 128 + mh * 64 + m * 16 + l15) * 64
                                        + ((ks * 4 + l4) ^ xrd) * 8);
  };
  auto mma = [&](int mh, int nh) {
    asm volatile("s_waitcnt lgkmcnt(0)" ::: "memory");
    __builtin_amdgcn_sched_barrier(0);
    __builtin_amdgcn_s_setprio(1);
#pragma unroll
    for (int m = 0; m < 4; ++m)
#pragma unroll
      for (int n = 0; n < 2; ++n)
#pragma unroll
        for (int ks = 0; ks < 2; ++ks)
          acc[mh * 4 + m][nh * 2 + n] = __builtin_amdgcn_mfma_f32_16x16x32_bf16(
              af[m][ks], bfr[nh * 2 + n][ks], acc[mh * 4 + m][nh * 2 + n], 0, 0, 0);
    __builtin_amdgcn_s_setprio(0);
  };

  const int NI = NT >> 1;
  for (int it = 0; it < NI; ++it) {
    const int T0 = 2 * it, T1 = 2 * it + 1;
    const bool pre = (it + 1 < NI);
    const bf16_t* sA0 = smem;
    const bf16_t* sB0 = smem + 16384;
    const bf16_t* sA1 = smem + 32768;
    const bf16_t* sB1 = smem + 49152;

    rdB(sB0, 0); rdA(sA0, 0);
    stB_H1(T1);
    __builtin_amdgcn_s_barrier();
    mma(0, 0);
    __builtin_amdgcn_s_barrier();
    rdB(sB0, 1);
    if (pre) stA_SP0(T0 + 2);
    __builtin_amdgcn_s_barrier();
    mma(0, 1);
    __builtin_amdgcn_s_barrier();
    rdA(sA0, 1);
    if (pre) stB_H0(T0 + 2);
    __builtin_amdgcn_s_barrier();
    mma(1, 0);
    __builtin_amdgcn_s_barrier();
    if (pre) stA_SP1(T0 + 2);
    __builtin_amdgcn_s_barrier();
    mma(1, 1);
    if (pre) { asm volatile("s_waitcnt vmcnt(6)" ::: "memory"); }
    else     { asm volatile("s_waitcnt vmcnt(0)" ::: "memory"); }
    __builtin_amdgcn_s_barrier();

    rdB(sB1, 0); rdA(sA1, 0);
    if (pre) stB_H1(T0 + 2);
    __builtin_amdgcn_s_barrier();
    mma(0, 0);
    __builtin_amdgcn_s_barrier();
    rdB(sB1, 1);
    if (pre) stA_SP0(T1 + 2);
    __builtin_amdgcn_s_barrier();
    mma(0, 1);
    __builtin_amdgcn_s_barrier();
    rdA(sA1, 1);
    if (pre) stB_H0(T1 + 2);
    __builtin_amdgcn_s_barrier();
    mma(1, 0);
    __builtin_amdgcn_s_barrier();
    if (pre) stA_SP1(T1 + 2);
    __builtin_amdgcn_s_barrier();
    mma(1, 1);
    if (pre) { asm volatile("s_waitcnt vmcnt(6)" ::: "memory"); }
    __builtin_amdgcn_s_barrier();
  }

  const int row_base = bm * 256 + wm * 128;
#pragma unroll
  for (int m = 0; m < 8; ++m) {
#pragma unroll
    for (int n = 0; n < 4; ++n) {
      int colg = bn * 256 + wn * 64 + n * 16 + l15;
#pragma unroll
      for (int r = 0; r < 4; ++r) {
        int row = row_base + m * 16 + l4 * 4 + r;
        float val = acc[m][n][r];
        if (EPI == 4) {
          outf[(size_t)row * Nst + col0 + colg] = val;
        } else if (EPI == 2) {
          int col = col0 + colg;
          float v2 = val + bias[col];
          v2 = 0.5f * v2 * (1.0f + erff(v2 * 0.7071067811865475f));
          outb[(size_t)row * Nst + col] = (bf16_t)v2;
        } else {
          int buf = colg >> 10;
          int lc  = colg & 1023;
          (outb + (size_t)buf * 4194304)[(size_t)row * 1024 + lc] = (bf16_t)val;
        }
      }
    }
  }
}

// ---------------- flash attention (causal), 1 block = (b, h, 128 q-rows), 8 waves ----------------
// K/V staged once per 128 q-rows (halves staging vs 64-row blocks); V column-rotated
// (2-way bank aliasing only); per-wave guard skips fully-masked k-tiles.
__global__ __launch_bounds__(512) void attn_kernel(
    const bf16_t* __restrict__ q, const bf16_t* __restrict__ k,
    const bf16_t* __restrict__ v, bf16_t* __restrict__ y) {
  int bid = blockIdx.x;
  int qt = bid & 7;               // L/128 = 8
  int h  = (bid >> 3) & (H_ - 1);
  int b  = bid >> 7;
  int tid = threadIdx.x, wid = tid >> 6, lane = tid & 63;
  int l15 = lane & 15, l4 = lane >> 4;

  __shared__ __align__(16) bf16_t Ks[64 * 72];
  __shared__ __align__(16) bf16_t Vs[64 * 72];
  __shared__ __align__(16) bf16_t Ps[8][16 * 72];

  const int qrow0 = qt * 128 + wid * 16;
  const int qmax  = qrow0 + 15;
  const size_t bh = ((size_t)b * L_ * H_ + h) * HD_;

  bf16x8 qf[2];
#pragma unroll
  for (int c = 0; c < 2; ++c)
    qf[c] = *(const bf16x8*)(q + bh + (size_t)(qrow0 + l15) * (H_ * HD_) + c * 32 + l4 * 8);

  float m_r[4] = {-INFINITY, -INFINITY, -INFINITY, -INFINITY};
  float l_r[4] = {0.f, 0.f, 0.f, 0.f};
  f32x4 oacc[4] = {};

  const int ktmax = 2 * qt + 1;
  for (int kt = 0; kt <= ktmax; ++kt) {
    __syncthreads();
    int kbase = kt * 64;
    {
      int j = tid >> 3;                      // 0..63
      int dof = (tid & 7) * 8;               // 0..56
      const size_t src = bh + (size_t)(kbase + j) * (H_ * HD_) + dof;
      *(bf16x8*)(Ks + j * 72 + dof) = *(const bf16x8*)(k + src);
      bf16x8 vv = *(const bf16x8*)(v + src);
      int colb = (j + dof) & 63;
#pragma unroll
      for (int jj = 0; jj < 8; ++jj) Vs[(dof + jj) * 72 + colb] = vv[jj];
    }
    __syncthreads();

    if (kbase > qmax) continue;              // fully masked for this wave

    f32x4 sacc[4] = {};
#pragma unroll
    for (int c = 0; c < 2; ++c) {
#pragma unroll
      for (int t = 0; t < 4; ++t) {
        bf16x8 kf = *(const bf16x8*)(Ks + (t * 16 + l15) * 72 + c * 32 + l4 * 8);
        sacc[t] = __builtin_amdgcn_mfma_f32_16x16x32_bf16(qf[c], kf, sacc[t], 0, 0, 0);
      }
    }

    float tmax[4] = {-INFINITY, -INFINITY, -INFINITY, -INFINITY};
#pragma unroll
    for (int t = 0; t < 4; ++t) {
#pragma unroll
      for (int r = 0; r < 4; ++r) {
        float sv = sacc[t][r] * 0.125f;
        int kj = kbase + t * 16 + l15;
        int qi = qrow0 + l4 * 4 + r;
        if (kj > qi) sv = -INFINITY;
        sacc[t][r] = sv;
        tmax[r] = fmaxf(tmax[r], sv);
      }
    }
#pragma unroll
    for (int r = 0; r < 4; ++r) {
#pragma unroll
      for (int md = 1; md < 16; md <<= 1)
        tmax[r] = fmaxf(tmax[r], __shfl_xor(tmax[r], md));
    }
    float alpha[4], tsum[4];
#pragma unroll
    for (int r = 0; r < 4; ++r) {
      float mn = fmaxf(m_r[r], tmax[r]);
      alpha[r] = expf(m_r[r] - mn);
      m_r[r] = mn;
      tsum[r] = 0.f;
    }
#pragma unroll
    for (int t = 0; t < 4; ++t) {
#pragma unroll
      for (int r = 0; r < 4; ++r) {
        float p = expf(sacc[t][r] - m_r[r]);
        tsum[r] += p;
        Ps[wid][(l4 * 4 + r) * 72 + t * 16 + l15] = (bf16_t)p;
      }
    }
#pragma unroll
    for (int r = 0; r < 4; ++r) {
#pragma unroll
      for (int md = 1; md < 16; md <<= 1)
        tsum[r] += __shfl_xor(tsum[r], md);
      l_r[r] = l_r[r] * alpha[r] + tsum[r];
    }
#pragma unroll
    for (int t = 0; t < 4; ++t)
#pragma unroll
      for (int r = 0; r < 4; ++r)
        oacc[t][r] *= alpha[r];

#pragma unroll
    for (int c = 0; c < 2; ++c) {
      bf16x8 pf = *(const bf16x8*)(&Ps[wid][l15 * 72 + c * 32 + l4 * 8]);
#pragma unroll
      for (int t = 0; t < 4; ++t) {
        int d = t * 16 + l15;
        int jb = c * 32 + l4 * 8;
        bf16x8 vf = *(const bf16x8*)(Vs + d * 72 + ((jb + (d & 56)) & 63));
        oacc[t] = __builtin_amdgcn_mfma_f32_16x16x32_bf16(pf, vf, oacc[t], 0, 0, 0);
      }
    }
  }

#pragma unroll
  for (int t = 0; t < 4; ++t) {
#pragma unroll
    for (int r = 0; r < 4; ++r) {
      int row = qrow0 + l4 * 4 + r;
      int d = t * 16 + l15;
      y[bh + (size_t)row * (H_ * HD_) + d] = (bf16_t)(oacc[t][r] / l_r[r]);
    }
  }
}

// ---------------- host launcher ----------------
extern "C" void kernel_launch(void* const* d_in, const int* in_sizes, int n_in,
                              void* d_out, int out_size, void* d_ws, size_t ws_size,
                              hipStream_t stream) {
  (void)in_sizes; (void)n_in; (void)out_size;
  const int*   idx   = (const int*)d_in[0];
  const float* emb   = (const float*)d_in[1];
  const float* ln1_s = (const float*)d_in[2];
  const float* ln1_b = (const float*)d_in[3];
  const float* wq    = (const float*)d_in[4];
  const float* wk    = (const float*)d_in[5];
  const float* wv    = (const float*)d_in[6];
  const float* wo    = (const float*)d_in[7];
  const float* ln2_s = (const float*)d_in[8];
  const float* ln2_b = (const float*)d_in[9];
  const float* w1    = (const float*)d_in[10];
  const float* b1    = (const float*)d_in[11];
  const float* w2    = (const float*)d_in[12];
  const float* b2    = (const float*)d_in[13];
  const float* lnf_s = (const float*)d_in[14];
  const float* lnf_b = (const float*)d_in[15];
  const float* headw = (const float*)d_in[16];
  float* out = (float*)d_out;

  char* ws = (char*)d_ws;
  const size_t XO  = 0;
  const size_t HBO = XO  + 16777216;     // f32 residual 4096x1024
  const size_t QBO = HBO + 8388608;      // bf16 4096x1024 each; Q,K,V contiguous
  const size_t KBO = QBO + 8388608;
  const size_t VBO = KBO + 8388608;
  const size_t YBO = VBO + 8388608;
  const size_t GBO = QBO;                // FFN intermediate overlaps Q/K/V/Y
  const size_t WTO = YBO + 8388608;      // weight-transpose staging region
  const size_t LBYTES = 25165824;        // 24 MB per layer (qkv 6 + wo 2 + w1 8 + w2 8)
  const size_t LELEMS = LBYTES / 2;
  const bool prepass = ws_size >= WTO + (size_t)NL_ * LBYTES;

  float*  X   = (float*)(ws + XO);
  bf16_t* Hb  = (bf16_t*)(ws + HBO);
  bf16_t* Qb  = (bf16_t*)(ws + QBO);
  bf16_t* Kb  = (bf16_t*)(ws + KBO);
  bf16_t* Vb  = (bf16_t*)(ws + VBO);
  bf16_t* Yb  = (bf16_t*)(ws + YBO);
  bf16_t* Gb  = (bf16_t*)(ws + GBO);
  bf16_t* Wbase = (bf16_t*)(ws + WTO);
  bf16_t* WT    = (bf16_t*)(ws + WTO);   // head transpose reuses region after layers

  const int M = B_ * L_;                 // 4096
  const dim3 tb16(16, 16);

  embed_kernel<<<M, 256, 0, stream>>>(idx, emb, X);

  if (prepass)
    transpose_all<<<NL_ * 3072, tb16, 0, stream>>>(wq, wk, wv, wo, w1, w2, 0, Wbase, LELEMS);

  for (int l = 0; l < NL_; ++l) {
    bf16_t* wl = prepass ? (Wbase + (size_t)l * LELEMS) : Wbase;
    bf16_t* qkvT = wl;
    bf16_t* woT  = wl + 3145728;
    bf16_t* w1T  = wl + 4194304;
    bf16_t* w2T  = wl + 8388608;

    ln_kernel<<<M, 256, 0, stream>>>(X, ln1_s + (size_t)l * D_, ln1_b + (size_t)l * D_, Hb);

    if (!prepass)
      transpose_all<<<3072, tb16, 0, stream>>>(wq, wk, wv, wo, w1, w2, l, Wbase, 0);

    gemm256_kernel<5><<<dim3(3*D_/256, M/256), 512, 0, stream>>>(Hb, qkvT, Qb, nullptr, nullptr, M, D_, D_, 0);

    attn_kernel<<<B_ * H_ * (L_/128), 512, 0, stream>>>(Qb, Kb, Vb, Yb);

    gemm_bt_kernel<1><<<dim3(D_/128, M/128, 2), 256, 0, stream>>>(Yb, woT, nullptr, X, nullptr, M, D_, D_, 0);

    ln_kernel<<<M, 256, 0, stream>>>(X, ln2_s + (size_t)l * D_, ln2_b + (size_t)l * D_, Hb);

    gemm256_kernel<2><<<dim3(FF_/256, M/256), 512, 0, stream>>>(Hb, w1T, Gb, nullptr, b1 + (size_t)l * FF_, M, FF_, D_, 0);

    gemm_bt_kernel<3><<<dim3(D_/128, M/128, 4), 256, 0, stream>>>(Gb, w2T, nullptr, X, b2 + (size_t)l * D_, M, D_, FF_, 0);
  }

  ln_kernel<<<M, 256, 0, stream>>>(X, lnf_s, lnf_b, Hb);

  // head GEMM -> f32 logits, single chunk when ws allows
  size_t avail = (ws_size > WTO) ? (ws_size - WTO) : 0;
  long long maxcols = (long long)(avail / ((size_t)D_ * 2));
  int chunk = (int)((maxcols / 256) * 256);
  if (chunk > V_) chunk = V_;
  if (chunk < 256) chunk = 256;
  for (int n0 = 0; n0 < V_; n0 += chunk) {
    int nc = (V_ - n0 < chunk) ? (V_ - n0) : chunk;
    transpose64_k<<<dim3(nc/64, D_/64), tb16, 0, stream>>>(headw, (size_t)n0, WT, D_, V_);
    gemm256_kernel<4><<<dim3(nc/256, M/256), 512, 0, stream>>>(Hb, WT, nullptr, out, nullptr, M, V_, D_, n0);
  }
}

// Round 15
// 2648.632 us; speedup vs baseline: 1.1431x; 1.1147x over previous
//
#include <hip/hip_runtime.h>
#include <hip/hip_bf16.h>
#include <math.h>

typedef __bf16 bf16_t;
typedef __attribute__((ext_vector_type(8))) __bf16 bf16x8;
typedef __attribute__((ext_vector_type(4))) __bf16 bf16x4;
typedef __attribute__((ext_vector_type(4))) float f32x4;

#define B_  4
#define L_  1024
#define D_  1024
#define H_  16
#define HD_ 64
#define NL_ 8
#define V_  32000
#define FF_ 4096

// ---------------- embed + sinusoidal PE -> f32 residual ----------------
__global__ __launch_bounds__(256) void embed_kernel(const int* __restrict__ idx,
                                                    const float* __restrict__ emb,
                                                    float* __restrict__ x) {
  int token = blockIdx.x;           // b*L + l
  int l = token & (L_ - 1);
  int id = idx[token];
  const float* erow = emb + (size_t)id * D_;
  float* xrow = x + (size_t)token * D_;
  int d0 = threadIdx.x * 4;
#pragma unroll
  for (int j = 0; j < 4; ++j) {
    int d = d0 + j;
    int i = d >> 1;
    float freq = expf((float)(2 * i) * (-9.210340371976184f / (float)D_));
    float ang = (float)l * freq;
    float pe = (d & 1) ? cosf(ang) : sinf(ang);
    xrow[d] = erow[d] + pe;
  }
}

// ---------------- LayerNorm: f32 in -> bf16 out (plain) ----------------
__global__ __launch_bounds__(256) void ln_kernel(const float* __restrict__ x,
                                                 const float* __restrict__ gamma,
                                                 const float* __restrict__ beta,
                                                 bf16_t* __restrict__ out) {
  int row = blockIdx.x;
  int t = threadIdx.x;
  float4 v = ((const float4*)(x + (size_t)row * D_))[t];
  float va[4] = {v.x, v.y, v.z, v.w};
  float s = va[0] + va[1] + va[2] + va[3];
  float ss = va[0]*va[0] + va[1]*va[1] + va[2]*va[2] + va[3]*va[3];
#pragma unroll
  for (int m = 1; m < 64; m <<= 1) {
    s  += __shfl_xor(s, m);
    ss += __shfl_xor(ss, m);
  }
  __shared__ float red[8];
  int wid = t >> 6, lane = t & 63;
  if (lane == 0) { red[wid] = s; red[4 + wid] = ss; }
  __syncthreads();
  s  = red[0] + red[1] + red[2] + red[3];
  ss = red[4] + red[5] + red[6] + red[7];
  float mu  = s * (1.0f / D_);
  float var = fmaxf(ss * (1.0f / D_) - mu * mu, 0.0f);
  float rstd = rsqrtf(var + 1e-5f);
  int d0 = t * 4;
  bf16_t* orow = out + (size_t)row * D_ + d0;
#pragma unroll
  for (int j = 0; j < 4; ++j) {
    int d = d0 + j;
    orow[j] = (bf16_t)((va[j] - mu) * rstd * gamma[d] + beta[d]);
  }
}

// ---- fused: X += sum(partials) (+bias); write X; LayerNorm(X) -> bf16 out ----
template <int NP>
__global__ __launch_bounds__(256) void ln_red_kernel(
    float* __restrict__ x, const float* __restrict__ part,
    const float* __restrict__ bias,
    const float* __restrict__ gamma, const float* __restrict__ beta,
    bf16_t* __restrict__ out) {
  int row = blockIdx.x;
  int t = threadIdx.x;
  size_t rb = (size_t)row * D_;
  float4 v = ((const float4*)(x + rb))[t];
  float va[4] = {v.x, v.y, v.z, v.w};
#pragma unroll
  for (int p = 0; p < NP; ++p) {
    float4 pv = ((const float4*)(part + (size_t)p * 4194304 + rb))[t];
    va[0] += pv.x; va[1] += pv.y; va[2] += pv.z; va[3] += pv.w;
  }
  if (bias) {
    float4 bv = ((const float4*)bias)[t];
    va[0] += bv.x; va[1] += bv.y; va[2] += bv.z; va[3] += bv.w;
  }
  ((float4*)(x + rb))[t] = make_float4(va[0], va[1], va[2], va[3]);
  float s = va[0] + va[1] + va[2] + va[3];
  float ss = va[0]*va[0] + va[1]*va[1] + va[2]*va[2] + va[3]*va[3];
#pragma unroll
  for (int m = 1; m < 64; m <<= 1) {
    s  += __shfl_xor(s, m);
    ss += __shfl_xor(ss, m);
  }
  __shared__ float red[8];
  int wid = t >> 6, lane = t & 63;
  if (lane == 0) { red[wid] = s; red[4 + wid] = ss; }
  __syncthreads();
  s  = red[0] + red[1] + red[2] + red[3];
  ss = red[4] + red[5] + red[6] + red[7];
  float mu  = s * (1.0f / D_);
  float var = fmaxf(ss * (1.0f / D_) - mu * mu, 0.0f);
  float rstd = rsqrtf(var + 1e-5f);
  int d0 = t * 4;
  bf16_t* orow = out + rb + d0;
#pragma unroll
  for (int j = 0; j < 4; ++j) {
    int d = d0 + j;
    orow[j] = (bf16_t)((va[j] - mu) * rstd * gamma[d] + beta[d]);
  }
}

// ---- 64x64 transpose tile body: in[k][n] (f32, row stride ldin) -> out[n][k] (bf16) ----
__device__ __forceinline__ void tr64_body(const float* __restrict__ in, bf16_t* __restrict__ out,
                                          int K, int ldin, int n0, int k0) {
  __shared__ bf16_t tile[64][66];
  int tx = threadIdx.x, ty = threadIdx.y;   // 16 x 16
#pragma unroll
  for (int r = 0; r < 4; ++r) {
    int kk = ty + r * 16;
    float4 v = *(const float4*)(in + (size_t)(k0 + kk) * ldin + n0 + tx * 4);
    tile[kk][tx * 4 + 0] = (bf16_t)v.x;
    tile[kk][tx * 4 + 1] = (bf16_t)v.y;
    tile[kk][tx * 4 + 2] = (bf16_t)v.z;
    tile[kk][tx * 4 + 3] = (bf16_t)v.w;
  }
  __syncthreads();
#pragma unroll
  for (int r = 0; r < 4; ++r) {
    int nn = ty + r * 16;
    bf16x4 w;
    w[0] = tile[tx * 4 + 0][nn];
    w[1] = tile[tx * 4 + 1][nn];
    w[2] = tile[tx * 4 + 2][nn];
    w[3] = tile[tx * 4 + 3][nn];
    *(bf16x4*)(out + (size_t)(n0 + nn) * K + k0 + tx * 4) = w;
  }
}

// ------- head-chunk transpose: in[k][base+n] -> out[n][k] -------
__global__ void transpose64_k(const float* __restrict__ in, size_t base,
                              bf16_t* __restrict__ out, int K, int ldin) {
  tr64_body(in + base, out, K, ldin, blockIdx.x * 64, blockIdx.y * 64);
}

// ------- all-weights transpose (nlayers x 3072 tiles of 64x64) -------
__global__ void transpose_all(const float* __restrict__ wq, const float* __restrict__ wk,
                              const float* __restrict__ wv, const float* __restrict__ wo,
                              const float* __restrict__ w1, const float* __restrict__ w2,
                              int lbase, bf16_t* __restrict__ outbase, size_t lstride) {
  int b = blockIdx.x;
  int li = b / 3072, t = b % 3072;
  int l = lbase + li;
  bf16_t* wl = outbase + (size_t)li * lstride;
  const size_t wofD = (size_t)l * D_ * D_;
  const size_t wofF = (size_t)l * D_ * FF_;
  const float* in; bf16_t* out; int K, ldin, x, y;
  if (t < 768) {
    int z = t >> 8, tt = t & 255;
    in = (z == 0 ? wq : z == 1 ? wk : wv) + wofD;
    out = wl + (size_t)z * D_ * D_;
    K = D_; ldin = D_; x = tt & 15; y = tt >> 4;
  } else if (t < 1024) {
    int tt = t - 768;
    in = wo + wofD; out = wl + 3145728;
    K = D_; ldin = D_; x = tt & 15; y = tt >> 4;
  } else if (t < 2048) {
    int tt = t - 1024;
    in = w1 + wofF; out = wl + 4194304;
    K = D_; ldin = FF_; x = tt & 63; y = tt >> 6;
  } else {
    int tt = t - 2048;
    in = w2 + wofF; out = wl + 8388608;
    K = FF_; ldin = D_; x = tt & 15; y = tt >> 4;
  }
  tr64_body(in, out, K, ldin, x * 64, y * 64);
}

// ---------------- async global->LDS helper ----------------
__device__ __forceinline__ void gload_lds16(const bf16_t* g, bf16_t* lds) {
  __builtin_amdgcn_global_load_lds(
      (const __attribute__((address_space(1))) void*)g,
      (__attribute__((address_space(3))) void*)(void*)lds,
      16, 0, 0);
}

// ---- common bijective XCD + grouped-raster block remap (G=8 bm rows/group) ----
__device__ __forceinline__ void remap_block(int& bn, int& bm) {
  const int gx = gridDim.x, gy = gridDim.y;
  int lin = blockIdx.y * gx + blockIdx.x;
  int nwg = gx * gy;
  int q8 = nwg >> 3, r8 = nwg & 7;
  int xcd = lin & 7, pos = lin >> 3;
  int wg = (xcd < r8 ? xcd * (q8 + 1) : r8 * (q8 + 1) + (xcd - r8) * q8) + pos;
  if ((gy & 7) == 0) {
    int per = gx << 3;
    int grp = wg / per, win = wg % per;
    bm = (grp << 3) + (win & 7);
    bn = win >> 3;
  } else { bn = wg % gx; bm = wg / gx; }
}

// ---------------- 128x128 GEMM (m97 structure) with split-K over blockIdx.z ----------------
// EPI: 1 = atomicAdd resid; 3 = atomicAdd resid (+bias on split 0); 5 = store partial[z]
template <int EPI>
__global__ __launch_bounds__(256) void gemm_bt_kernel(
    const bf16_t* __restrict__ A, const bf16_t* __restrict__ Bt,
    bf16_t* __restrict__ outb, float* __restrict__ outf,
    const float* __restrict__ bias, int M, int Nst, int K, int col0) {
  int bn, bm; remap_block(bn, bm);
  const int kz = blockIdx.z, KS = gridDim.z;
  const int Kc = K / KS;
  const int kbeg = kz * Kc, kend = kbeg + Kc;
  const int tid = threadIdx.x, wid = tid >> 6, lane = tid & 63;
  const int wm = wid >> 1, wn = wid & 1;
  const int l15 = lane & 15, l4 = lane >> 4;

  __shared__ __align__(16) bf16_t As[128 * 32];
  __shared__ __align__(16) bf16_t Bs[128 * 32];

  f32x4 acc[4][4] = {};

  const bf16_t* Ablk = A  + (size_t)(bm * 128) * K;
  const bf16_t* Bblk = Bt + (size_t)(bn * 128) * K;
  const int srow = lane >> 2;
  const int skof = (lane & 3) * 8;

  for (int k0 = kbeg; k0 < kend; k0 += 32) {
#pragma unroll
    for (int c = 0; c < 2; ++c) {
      int chunk = wid * 2 + c;
      int row = chunk * 16 + srow;
      gload_lds16(Ablk + (size_t)row * K + k0 + skof, As + chunk * 512);
      gload_lds16(Bblk + (size_t)row * K + k0 + skof, Bs + chunk * 512);
    }
    __syncthreads();

    bf16x8 af[4], bfv[4];
#pragma unroll
    for (int i = 0; i < 4; ++i)
      af[i] = *(const bf16x8*)(As + (wm * 64 + i * 16 + l15) * 32 + l4 * 8);
#pragma unroll
    for (int j = 0; j < 4; ++j)
      bfv[j] = *(const bf16x8*)(Bs + (wn * 64 + j * 16 + l15) * 32 + l4 * 8);
#pragma unroll
    for (int i = 0; i < 4; ++i)
#pragma unroll
      for (int j = 0; j < 4; ++j)
        acc[i][j] = __builtin_amdgcn_mfma_f32_16x16x32_bf16(af[i], bfv[j], acc[i][j], 0, 0, 0);
    __syncthreads();
  }

  const int row_base = bm * 128 + wm * 64;
  const int col_base = col0 + bn * 128 + wn * 64 + l15;
#pragma unroll
  for (int i = 0; i < 4; ++i) {
#pragma unroll
    for (int j = 0; j < 4; ++j) {
      int col = col_base + j * 16;
#pragma unroll
      for (int r = 0; r < 4; ++r) {
        int row = row_base + i * 16 + l4 * 4 + r;
        float val = acc[i][j][r];
        if (EPI == 5) {
          outf[(size_t)kz * 4194304 + (size_t)row * Nst + col] = val;
        } else {
          if (EPI == 3 && kz == 0) val += bias[col];
          atomicAdd(&outf[(size_t)row * Nst + col], val);
        }
      }
    }
  }
}

// ------- 256x256 8-wave GEMM, BK=64, 8-phase schedule, race-free stage map -------
// EPI: 2 = +bias,gelu,bf16; 4 = f32; 5 = QKV split
template <int EPI>
__global__ __launch_bounds__(512, 2) void gemm256_kernel(
    const bf16_t* __restrict__ A, const bf16_t* __restrict__ Bt,
    bf16_t* __restrict__ outb, float* __restrict__ outf,
    const float* __restrict__ bias, int M, int Nst, int K, int col0) {
  int bn, bm; remap_block(bn, bm);
  const int tid = threadIdx.x, wid = tid >> 6, lane = tid & 63;
  const int wm = wid >> 2, wn = wid & 3;          // 2 x 4 waves
  const int l15 = lane & 15, l4 = lane >> 4;

  __shared__ __align__(16) bf16_t smem[65536];

  f32x4 acc[8][4] = {};

  const bf16_t* Ab = A  + (size_t)(bm * 256) * K;
  const bf16_t* Bb = Bt + (size_t)(bn * 256) * K;
  const int NT = K >> 6;

  const int srow = tid >> 3;
  const int sx8  = tid & 7;
  const int xrd  = l15 & 7;

  auto stage_rows = [&](int t, int mat, int R) {
    const bf16_t* g = mat ? Bb : Ab;
    bf16_t* l = smem + (t & 1) * 32768 + mat * 16384 + R * 64;
    int row = R + srow;
    int gs  = sx8 ^ (row & 7);
    gload_lds16(g + (size_t)row * K + t * 64 + gs * 8, l + wid * 512);
  };
  auto stA_SP0 = [&](int t) { stage_rows(t, 0, 0);   stage_rows(t, 0, 128); };
  auto stA_SP1 = [&](int t) { stage_rows(t, 0, 64);  stage_rows(t, 0, 192); };
  auto stB_H0  = [&](int t) { stage_rows(t, 1, 0);   stage_rows(t, 1, 64);  };
  auto stB_H1  = [&](int t) { stage_rows(t, 1, 128); stage_rows(t, 1, 192); };

  stA_SP0(0); stB_H0(0); stA_SP1(0); stB_H1(0);
  stA_SP0(1); stB_H0(1); stA_SP1(1);
  asm volatile("s_waitcnt vmcnt(6)" ::: "memory");
  __builtin_amdgcn_s_barrier();

  bf16x8 af[4][2], bfr[4][2];

  auto rdB = [&](const bf16_t* sB, int nh) {
#pragma unroll
    for (int n = 0; n < 2; ++n)
#pragma unroll
      for (int ks = 0; ks < 2; ++ks)
        bfr[nh * 2 + n][ks] = *(const bf16x8*)(sB + (wn * 64 + (nh * 2 + n) * 16 + l15) * 64
                                                  + ((ks * 4 + l4) ^ xrd) * 8);
  };
  auto rdA = [&](const bf16_t* sA, int mh) {
#pragma unroll
    for (int m = 0; m < 4; ++m)
#pragma unroll
      for (int ks = 0; ks < 2; ++ks)
        af[m][ks] = *(const bf16x8*)(sA + (wm * 128 + mh * 64 + m * 16 + l15) * 64
                                        + ((ks * 4 + l4) ^ xrd) * 8);
  };
  auto mma = [&](int mh, int nh) {
    asm volatile("s_waitcnt lgkmcnt(0)" ::: "memory");
    __builtin_amdgcn_sched_barrier(0);
    __builtin_amdgcn_s_setprio(1);
#pragma unroll
    for (int m = 0; m < 4; ++m)
#pragma unroll
      for (int n = 0; n < 2; ++n)
#pragma unroll
        for (int ks = 0; ks < 2; ++ks)
          acc[mh * 4 + m][nh * 2 + n] = __builtin_amdgcn_mfma_f32_16x16x32_bf16(
              af[m][ks], bfr[nh * 2 + n][ks], acc[mh * 4 + m][nh * 2 + n], 0, 0, 0);
    __builtin_amdgcn_s_setprio(0);
  };

  const int NI = NT >> 1;
  for (int it = 0; it < NI; ++it) {
    const int T0 = 2 * it, T1 = 2 * it + 1;
    const bool pre = (it + 1 < NI);
    const bf16_t* sA0 = smem;
    const bf16_t* sB0 = smem + 16384;
    const bf16_t* sA1 = smem + 32768;
    const bf16_t* sB1 = smem + 49152;

    rdB(sB0, 0); rdA(sA0, 0);
    stB_H1(T1);
    asm volatile("s_waitcnt lgkmcnt(8)" ::: "memory");   // B-reads drained pre-barrier
    __builtin_amdgcn_s_barrier();
    mma(0, 0);
    __builtin_amdgcn_s_barrier();
    rdB(sB0, 1);
    if (pre) stA_SP0(T0 + 2);
    __builtin_amdgcn_s_barrier();
    mma(0, 1);
    __builtin_amdgcn_s_barrier();
    rdA(sA0, 1);
    if (pre) stB_H0(T0 + 2);
    __builtin_amdgcn_s_barrier();
    mma(1, 0);
    __builtin_amdgcn_s_barrier();
    if (pre) stA_SP1(T0 + 2);
    __builtin_amdgcn_s_barrier();
    mma(1, 1);
    if (pre) { asm volatile("s_waitcnt vmcnt(6)" ::: "memory"); }
    else     { asm volatile("s_waitcnt vmcnt(0)" ::: "memory"); }
    __builtin_amdgcn_s_barrier();

    rdB(sB1, 0); rdA(sA1, 0);
    if (pre) stB_H1(T0 + 2);
    asm volatile("s_waitcnt lgkmcnt(8)" ::: "memory");
    __builtin_amdgcn_s_barrier();
    mma(0, 0);
    __builtin_amdgcn_s_barrier();
    rdB(sB1, 1);
    if (pre) stA_SP0(T1 + 2);
    __builtin_amdgcn_s_barrier();
    mma(0, 1);
    __builtin_amdgcn_s_barrier();
    rdA(sA1, 1);
    if (pre) stB_H0(T1 + 2);
    __builtin_amdgcn_s_barrier();
    mma(1, 0);
    __builtin_amdgcn_s_barrier();
    if (pre) stA_SP1(T1 + 2);
    __builtin_amdgcn_s_barrier();
    mma(1, 1);
    if (pre) { asm volatile("s_waitcnt vmcnt(6)" ::: "memory"); }
    __builtin_amdgcn_s_barrier();
  }

  const int row_base = bm * 256 + wm * 128;
#pragma unroll
  for (int m = 0; m < 8; ++m) {
#pragma unroll
    for (int n = 0; n < 4; ++n) {
      int colg = bn * 256 + wn * 64 + n * 16 + l15;
#pragma unroll
      for (int r = 0; r < 4; ++r) {
        int row = row_base + m * 16 + l4 * 4 + r;
        float val = acc[m][n][r];
        if (EPI == 4) {
          outf[(size_t)row * Nst + col0 + colg] = val;
        } else if (EPI == 2) {
          int col = col0 + colg;
          float v2 = val + bias[col];
          v2 = 0.5f * v2 * (1.0f + erff(v2 * 0.7071067811865475f));
          outb[(size_t)row * Nst + col] = (bf16_t)v2;
        } else {
          int buf = colg >> 10;
          int lc  = colg & 1023;
          (outb + (size_t)buf * 4194304)[(size_t)row * 1024 + lc] = (bf16_t)val;
        }
      }
    }
  }
}

// ---------------- flash attention (causal), 1 block = (b, h, 128 q-rows), 8 waves ----------------
// softmax in log2 domain: S' = S * 0.125 * log2(e); p = exp2(S' - m') (v_exp_f32 native)
__global__ __launch_bounds__(512) void attn_kernel(
    const bf16_t* __restrict__ q, const bf16_t* __restrict__ k,
    const bf16_t* __restrict__ v, bf16_t* __restrict__ y) {
  int bid = blockIdx.x;
  int qt = bid & 7;               // L/128 = 8
  int h  = (bid >> 3) & (H_ - 1);
  int b  = bid >> 7;
  int tid = threadIdx.x, wid = tid >> 6, lane = tid & 63;
  int l15 = lane & 15, l4 = lane >> 4;

  __shared__ __align__(16) bf16_t Ks[64 * 72];
  __shared__ __align__(16) bf16_t Vs[64 * 72];
  __shared__ __align__(16) bf16_t Ps[8][16 * 72];

  const int qrow0 = qt * 128 + wid * 16;
  const int qmax  = qrow0 + 15;
  const size_t bh = ((size_t)b * L_ * H_ + h) * HD_;
  const float SCL = 0.125f * 1.44269504f;   // (1/sqrt(64)) * log2(e)

  bf16x8 qf[2];
#pragma unroll
  for (int c = 0; c < 2; ++c)
    qf[c] = *(const bf16x8*)(q + bh + (size_t)(qrow0 + l15) * (H_ * HD_) + c * 32 + l4 * 8);

  float m_r[4] = {-INFINITY, -INFINITY, -INFINITY, -INFINITY};
  float l_r[4] = {0.f, 0.f, 0.f, 0.f};
  f32x4 oacc[4] = {};

  const int ktmax = 2 * qt + 1;
  for (int kt = 0; kt <= ktmax; ++kt) {
    __syncthreads();
    int kbase = kt * 64;
    {
      int j = tid >> 3;
      int dof = (tid & 7) * 8;
      const size_t src = bh + (size_t)(kbase + j) * (H_ * HD_) + dof;
      *(bf16x8*)(Ks + j * 72 + dof) = *(const bf16x8*)(k + src);
      bf16x8 vv = *(const bf16x8*)(v + src);
      int colb = (j + dof) & 63;
#pragma unroll
      for (int jj = 0; jj < 8; ++jj) Vs[(dof + jj) * 72 + colb] = vv[jj];
    }
    __syncthreads();

    if (kbase > qmax) continue;

    f32x4 sacc[4] = {};
#pragma unroll
    for (int c = 0; c < 2; ++c) {
#pragma unroll
      for (int t = 0; t < 4; ++t) {
        bf16x8 kf = *(const bf16x8*)(Ks + (t * 16 + l15) * 72 + c * 32 + l4 * 8);
        sacc[t] = __builtin_amdgcn_mfma_f32_16x16x32_bf16(qf[c], kf, sacc[t], 0, 0, 0);
      }
    }

    float tmax[4] = {-INFINITY, -INFINITY, -INFINITY, -INFINITY};
#pragma unroll
    for (int t = 0; t < 4; ++t) {
#pragma unroll
      for (int r = 0; r < 4; ++r) {
        float sv = sacc[t][r] * SCL;
        int kj = kbase + t * 16 + l15;
        int qi = qrow0 + l4 * 4 + r;
        if (kj > qi) sv = -INFINITY;
        sacc[t][r] = sv;
        tmax[r] = fmaxf(tmax[r], sv);
      }
    }
#pragma unroll
    for (int r = 0; r < 4; ++r) {
#pragma unroll
      for (int md = 1; md < 16; md <<= 1)
        tmax[r] = fmaxf(tmax[r], __shfl_xor(tmax[r], md));
    }
    float alpha[4], tsum[4];
#pragma unroll
    for (int r = 0; r < 4; ++r) {
      float mn = fmaxf(m_r[r], tmax[r]);
      alpha[r] = exp2f(m_r[r] - mn);
      m_r[r] = mn;
      tsum[r] = 0.f;
    }
#pragma unroll
    for (int t = 0; t < 4; ++t) {
#pragma unroll
      for (int r = 0; r < 4; ++r) {
        float p = exp2f(sacc[t][r] - m_r[r]);
        tsum[r] += p;
        Ps[wid][(l4 * 4 + r) * 72 + t * 16 + l15] = (bf16_t)p;
      }
    }
#pragma unroll
    for (int r = 0; r < 4; ++r) {
#pragma unroll
      for (int md = 1; md < 16; md <<= 1)
        tsum[r] += __shfl_xor(tsum[r], md);
      l_r[r] = l_r[r] * alpha[r] + tsum[r];
    }
#pragma unroll
    for (int t = 0; t < 4; ++t)
#pragma unroll
      for (int r = 0; r < 4; ++r)
        oacc[t][r] *= alpha[r];

#pragma unroll
    for (int c = 0; c < 2; ++c) {
      bf16x8 pf = *(const bf16x8*)(&Ps[wid][l15 * 72 + c * 32 + l4 * 8]);
#pragma unroll
      for (int t = 0; t < 4; ++t) {
        int d = t * 16 + l15;
        int jb = c * 32 + l4 * 8;
        bf16x8 vf = *(const bf16x8*)(Vs + d * 72 + ((jb + (d & 56)) & 63));
        oacc[t] = __builtin_amdgcn_mfma_f32_16x16x32_bf16(pf, vf, oacc[t], 0, 0, 0);
      }
    }
  }

#pragma unroll
  for (int t = 0; t < 4; ++t) {
#pragma unroll
    for (int r = 0; r < 4; ++r) {
      int row = qrow0 + l4 * 4 + r;
      int d = t * 16 + l15;
      y[bh + (size_t)row * (H_ * HD_) + d] = (bf16_t)(oacc[t][r] / l_r[r]);
    }
  }
}

// ---------------- host launcher ----------------
extern "C" void kernel_launch(void* const* d_in, const int* in_sizes, int n_in,
                              void* d_out, int out_size, void* d_ws, size_t ws_size,
                              hipStream_t stream) {
  (void)in_sizes; (void)n_in; (void)out_size;
  const int*   idx   = (const int*)d_in[0];
  const float* emb   = (const float*)d_in[1];
  const float* ln1_s = (const float*)d_in[2];
  const float* ln1_b = (const float*)d_in[3];
  const float* wq    = (const float*)d_in[4];
  const float* wk    = (const float*)d_in[5];
  const float* wv    = (const float*)d_in[6];
  const float* wo    = (const float*)d_in[7];
  const float* ln2_s = (const float*)d_in[8];
  const float* ln2_b = (const float*)d_in[9];
  const float* w1    = (const float*)d_in[10];
  const float* b1    = (const float*)d_in[11];
  const float* w2    = (const float*)d_in[12];
  const float* b2    = (const float*)d_in[13];
  const float* lnf_s = (const float*)d_in[14];
  const float* lnf_b = (const float*)d_in[15];
  const float* headw = (const float*)d_in[16];
  float* out = (float*)d_out;

  char* ws = (char*)d_ws;
  const size_t XO  = 0;
  const size_t HBO = XO  + 16777216;
  const size_t QBO = HBO + 8388608;
  const size_t KBO = QBO + 8388608;
  const size_t VBO = KBO + 8388608;
  const size_t YBO = VBO + 8388608;
  const size_t GBO = QBO;
  const size_t WTO = YBO + 8388608;
  const size_t LBYTES = 25165824;
  const size_t LELEMS = LBYTES / 2;
  const size_t PREB = (size_t)NL_ * LBYTES;          // 201.3 MB prepass weights
  const size_t WOPO = WTO + PREB;                    // wo partials 2x16MB
  const size_t F2PO = WOPO + 33554432;               // ffn2 partials 4x16MB
  const size_t HWTO = F2PO + 67108864;               // head WT 64MB
  const size_t NEED = HWTO + (size_t)V_ * D_ * 2;    // ~426 MB
  const bool big = ws_size >= NEED;
  const bool prepass = big || (ws_size >= WTO + PREB);

  float*  X   = (float*)(ws + XO);
  bf16_t* Hb  = (bf16_t*)(ws + HBO);
  bf16_t* Qb  = (bf16_t*)(ws + QBO);
  bf16_t* Kb  = (bf16_t*)(ws + KBO);
  bf16_t* Vb  = (bf16_t*)(ws + VBO);
  bf16_t* Yb  = (bf16_t*)(ws + YBO);
  bf16_t* Gb  = (bf16_t*)(ws + GBO);
  bf16_t* Wbase = (bf16_t*)(ws + WTO);
  float*  woP = (float*)(ws + WOPO);
  float*  f2P = (float*)(ws + F2PO);

  const int M = B_ * L_;
  const dim3 tb16(16, 16);

  embed_kernel<<<M, 256, 0, stream>>>(idx, emb, X);

  if (prepass)
    transpose_all<<<NL_ * 3072, tb16, 0, stream>>>(wq, wk, wv, wo, w1, w2, 0, Wbase, LELEMS);

  for (int l = 0; l < NL_; ++l) {
    bf16_t* wl = prepass ? (Wbase + (size_t)l * LELEMS) : Wbase;
    bf16_t* qkvT = wl;
    bf16_t* woT  = wl + 3145728;
    bf16_t* w1T  = wl + 4194304;
    bf16_t* w2T  = wl + 8388608;

    if (big && l > 0) {
      ln_red_kernel<4><<<M, 256, 0, stream>>>(X, f2P, b2 + (size_t)(l - 1) * D_,
                                              ln1_s + (size_t)l * D_, ln1_b + (size_t)l * D_, Hb);
    } else {
      ln_kernel<<<M, 256, 0, stream>>>(X, ln1_s + (size_t)l * D_, ln1_b + (size_t)l * D_, Hb);
    }

    if (!prepass)
      transpose_all<<<3072, tb16, 0, stream>>>(wq, wk, wv, wo, w1, w2, l, Wbase, 0);

    gemm256_kernel<5><<<dim3(3*D_/256, M/256), 512, 0, stream>>>(Hb, qkvT, Qb, nullptr, nullptr, M, D_, D_, 0);

    attn_kernel<<<B_ * H_ * (L_/128), 512, 0, stream>>>(Qb, Kb, Vb, Yb);

    if (big) {
      gemm_bt_kernel<5><<<dim3(D_/128, M/128, 2), 256, 0, stream>>>(Yb, woT, nullptr, woP, nullptr, M, D_, D_, 0);
      ln_red_kernel<2><<<M, 256, 0, stream>>>(X, woP, nullptr,
                                              ln2_s + (size_t)l * D_, ln2_b + (size_t)l * D_, Hb);
    } else {
      gemm_bt_kernel<1><<<dim3(D_/128, M/128, 2), 256, 0, stream>>>(Yb, woT, nullptr, X, nullptr, M, D_, D_, 0);
      ln_kernel<<<M, 256, 0, stream>>>(X, ln2_s + (size_t)l * D_, ln2_b + (size_t)l * D_, Hb);
    }

    gemm256_kernel<2><<<dim3(FF_/256, M/256), 512, 0, stream>>>(Hb, w1T, Gb, nullptr, b1 + (size_t)l * FF_, M, FF_, D_, 0);

    if (big) {
      gemm_bt_kernel<5><<<dim3(D_/128, M/128, 4), 256, 0, stream>>>(Gb, w2T, nullptr, f2P, nullptr, M, D_, FF_, 0);
    } else {
      gemm_bt_kernel<3><<<dim3(D_/128, M/128, 4), 256, 0, stream>>>(Gb, w2T, nullptr, X, b2 + (size_t)l * D_, M, D_, FF_, 0);
    }
  }

  if (big) {
    ln_red_kernel<4><<<M, 256, 0, stream>>>(X, f2P, b2 + (size_t)(NL_ - 1) * D_, lnf_s, lnf_b, Hb);
    bf16_t* HWT = (bf16_t*)(ws + HWTO);
    transpose64_k<<<dim3(V_/64, D_/64), tb16, 0, stream>>>(headw, 0, HWT, D_, V_);
    gemm256_kernel<4><<<dim3(V_/256, M/256), 512, 0, stream>>>(Hb, HWT, nullptr, out, nullptr, M, V_, D_, 0);
  } else {
    ln_kernel<<<M, 256, 0, stream>>>(X, lnf_s, lnf_b, Hb);
    bf16_t* WT = (bf16_t*)(ws + WTO);
    size_t avail = (ws_size > WTO) ? (ws_size - WTO) : 0;
    long long maxcols = (long long)(avail / ((size_t)D_ * 2));
    int chunk = (int)((maxcols / 256) * 256);
    if (chunk > V_) chunk = V_;
    if (chunk < 256) chunk = 256;
    for (int n0 = 0; n0 < V_; n0 += chunk) {
      int nc = (V_ - n0 < chunk) ? (V_ - n0) : chunk;
      transpose64_k<<<dim3(nc/64, D_/64), tb16, 0, stream>>>(headw, (size_t)n0, WT, D_, V_);
      gemm256_kernel<4><<<dim3(nc/256, M/256), 512, 0, stream>>>(Hb, WT, nullptr, out, nullptr, M, V_, D_, n0);
    }
  }
}

// Round 16
// 2640.956 us; speedup vs baseline: 1.1465x; 1.0029x over previous
//
#include <hip/hip_runtime.h>
#include <hip/hip_bf16.h>
#include <math.h>

typedef __bf16 bf16_t;
typedef __attribute__((ext_vector_type(8))) __bf16 bf16x8;
typedef __attribute__((ext_vector_type(4))) __bf16 bf16x4;
typedef __attribute__((ext_vector_type(4))) float f32x4;

#define B_  4
#define L_  1024
#define D_  1024
#define H_  16
#define HD_ 64
#define NL_ 8
#define V_  32000
#define FF_ 4096

// ---------------- embed + sinusoidal PE -> f32 residual ----------------
__global__ __launch_bounds__(256) void embed_kernel(const int* __restrict__ idx,
                                                    const float* __restrict__ emb,
                                                    float* __restrict__ x) {
  int token = blockIdx.x;           // b*L + l
  int l = token & (L_ - 1);
  int id = idx[token];
  const float* erow = emb + (size_t)id * D_;
  float* xrow = x + (size_t)token * D_;
  int d0 = threadIdx.x * 4;
#pragma unroll
  for (int j = 0; j < 4; ++j) {
    int d = d0 + j;
    int i = d >> 1;
    float freq = expf((float)(2 * i) * (-9.210340371976184f / (float)D_));
    float ang = (float)l * freq;
    float pe = (d & 1) ? cosf(ang) : sinf(ang);
    xrow[d] = erow[d] + pe;
  }
}

// ---------------- LayerNorm: f32 in -> bf16 out (plain) ----------------
__global__ __launch_bounds__(256) void ln_kernel(const float* __restrict__ x,
                                                 const float* __restrict__ gamma,
                                                 const float* __restrict__ beta,
                                                 bf16_t* __restrict__ out) {
  int row = blockIdx.x;
  int t = threadIdx.x;
  float4 v = ((const float4*)(x + (size_t)row * D_))[t];
  float va[4] = {v.x, v.y, v.z, v.w};
  float s = va[0] + va[1] + va[2] + va[3];
  float ss = va[0]*va[0] + va[1]*va[1] + va[2]*va[2] + va[3]*va[3];
#pragma unroll
  for (int m = 1; m < 64; m <<= 1) {
    s  += __shfl_xor(s, m);
    ss += __shfl_xor(ss, m);
  }
  __shared__ float red[8];
  int wid = t >> 6, lane = t & 63;
  if (lane == 0) { red[wid] = s; red[4 + wid] = ss; }
  __syncthreads();
  s  = red[0] + red[1] + red[2] + red[3];
  ss = red[4] + red[5] + red[6] + red[7];
  float mu  = s * (1.0f / D_);
  float var = fmaxf(ss * (1.0f / D_) - mu * mu, 0.0f);
  float rstd = rsqrtf(var + 1e-5f);
  int d0 = t * 4;
  bf16_t* orow = out + (size_t)row * D_ + d0;
#pragma unroll
  for (int j = 0; j < 4; ++j) {
    int d = d0 + j;
    orow[j] = (bf16_t)((va[j] - mu) * rstd * gamma[d] + beta[d]);
  }
}

// ---- fused: X += sum(partials) (+bias); write X; LayerNorm(X) -> bf16 out ----
template <int NP>
__global__ __launch_bounds__(256) void ln_red_kernel(
    float* __restrict__ x, const float* __restrict__ part,
    const float* __restrict__ bias,
    const float* __restrict__ gamma, const float* __restrict__ beta,
    bf16_t* __restrict__ out) {
  int row = blockIdx.x;
  int t = threadIdx.x;
  size_t rb = (size_t)row * D_;
  float4 v = ((const float4*)(x + rb))[t];
  float va[4] = {v.x, v.y, v.z, v.w};
#pragma unroll
  for (int p = 0; p < NP; ++p) {
    float4 pv = ((const float4*)(part + (size_t)p * 4194304 + rb))[t];
    va[0] += pv.x; va[1] += pv.y; va[2] += pv.z; va[3] += pv.w;
  }
  if (bias) {
    float4 bv = ((const float4*)bias)[t];
    va[0] += bv.x; va[1] += bv.y; va[2] += bv.z; va[3] += bv.w;
  }
  ((float4*)(x + rb))[t] = make_float4(va[0], va[1], va[2], va[3]);
  float s = va[0] + va[1] + va[2] + va[3];
  float ss = va[0]*va[0] + va[1]*va[1] + va[2]*va[2] + va[3]*va[3];
#pragma unroll
  for (int m = 1; m < 64; m <<= 1) {
    s  += __shfl_xor(s, m);
    ss += __shfl_xor(ss, m);
  }
  __shared__ float red[8];
  int wid = t >> 6, lane = t & 63;
  if (lane == 0) { red[wid] = s; red[4 + wid] = ss; }
  __syncthreads();
  s  = red[0] + red[1] + red[2] + red[3];
  ss = red[4] + red[5] + red[6] + red[7];
  float mu  = s * (1.0f / D_);
  float var = fmaxf(ss * (1.0f / D_) - mu * mu, 0.0f);
  float rstd = rsqrtf(var + 1e-5f);
  int d0 = t * 4;
  bf16_t* orow = out + rb + d0;
#pragma unroll
  for (int j = 0; j < 4; ++j) {
    int d = d0 + j;
    orow[j] = (bf16_t)((va[j] - mu) * rstd * gamma[d] + beta[d]);
  }
}

// ---- 64x64 transpose tile body: in[k][n] (f32, row stride ldin) -> out[n][k] (bf16) ----
__device__ __forceinline__ void tr64_body(const float* __restrict__ in, bf16_t* __restrict__ out,
                                          int K, int ldin, int n0, int k0) {
  __shared__ bf16_t tile[64][66];
  int tx = threadIdx.x, ty = threadIdx.y;   // 16 x 16
#pragma unroll
  for (int r = 0; r < 4; ++r) {
    int kk = ty + r * 16;
    float4 v = *(const float4*)(in + (size_t)(k0 + kk) * ldin + n0 + tx * 4);
    tile[kk][tx * 4 + 0] = (bf16_t)v.x;
    tile[kk][tx * 4 + 1] = (bf16_t)v.y;
    tile[kk][tx * 4 + 2] = (bf16_t)v.z;
    tile[kk][tx * 4 + 3] = (bf16_t)v.w;
  }
  __syncthreads();
#pragma unroll
  for (int r = 0; r < 4; ++r) {
    int nn = ty + r * 16;
    bf16x4 w;
    w[0] = tile[tx * 4 + 0][nn];
    w[1] = tile[tx * 4 + 1][nn];
    w[2] = tile[tx * 4 + 2][nn];
    w[3] = tile[tx * 4 + 3][nn];
    *(bf16x4*)(out + (size_t)(n0 + nn) * K + k0 + tx * 4) = w;
  }
}

// ------- head-chunk transpose: in[k][base+n] -> out[n][k] -------
__global__ void transpose64_k(const float* __restrict__ in, size_t base,
                              bf16_t* __restrict__ out, int K, int ldin) {
  tr64_body(in + base, out, K, ldin, blockIdx.x * 64, blockIdx.y * 64);
}

// ------- all-weights transpose (nlayers x 3072 tiles of 64x64) -------
__global__ void transpose_all(const float* __restrict__ wq, const float* __restrict__ wk,
                              const float* __restrict__ wv, const float* __restrict__ wo,
                              const float* __restrict__ w1, const float* __restrict__ w2,
                              int lbase, bf16_t* __restrict__ outbase, size_t lstride) {
  int b = blockIdx.x;
  int li = b / 3072, t = b % 3072;
  int l = lbase + li;
  bf16_t* wl = outbase + (size_t)li * lstride;
  const size_t wofD = (size_t)l * D_ * D_;
  const size_t wofF = (size_t)l * D_ * FF_;
  const float* in; bf16_t* out; int K, ldin, x, y;
  if (t < 768) {
    int z = t >> 8, tt = t & 255;
    in = (z == 0 ? wq : z == 1 ? wk : wv) + wofD;
    out = wl + (size_t)z * D_ * D_;
    K = D_; ldin = D_; x = tt & 15; y = tt >> 4;
  } else if (t < 1024) {
    int tt = t - 768;
    in = wo + wofD; out = wl + 3145728;
    K = D_; ldin = D_; x = tt & 15; y = tt >> 4;
  } else if (t < 2048) {
    int tt = t - 1024;
    in = w1 + wofF; out = wl + 4194304;
    K = D_; ldin = FF_; x = tt & 63; y = tt >> 6;
  } else {
    int tt = t - 2048;
    in = w2 + wofF; out = wl + 8388608;
    K = FF_; ldin = D_; x = tt & 15; y = tt >> 4;
  }
  tr64_body(in, out, K, ldin, x * 64, y * 64);
}

// ---------------- async global->LDS helper ----------------
__device__ __forceinline__ void gload_lds16(const bf16_t* g, bf16_t* lds) {
  __builtin_amdgcn_global_load_lds(
      (const __attribute__((address_space(1))) void*)g,
      (__attribute__((address_space(3))) void*)(void*)lds,
      16, 0, 0);
}

// ---- common bijective XCD + grouped-raster block remap (G=8 bm rows/group) ----
__device__ __forceinline__ void remap_block(int& bn, int& bm) {
  const int gx = gridDim.x, gy = gridDim.y;
  int lin = blockIdx.y * gx + blockIdx.x;
  int nwg = gx * gy;
  int q8 = nwg >> 3, r8 = nwg & 7;
  int xcd = lin & 7, pos = lin >> 3;
  int wg = (xcd < r8 ? xcd * (q8 + 1) : r8 * (q8 + 1) + (xcd - r8) * q8) + pos;
  if ((gy & 7) == 0) {
    int per = gx << 3;
    int grp = wg / per, win = wg % per;
    bm = (grp << 3) + (win & 7);
    bn = win >> 3;
  } else { bn = wg % gx; bm = wg / gx; }
}

// ---------------- 128x128 GEMM (m97 structure) with split-K over blockIdx.z ----------------
// EPI: 1 = atomicAdd resid; 3 = atomicAdd resid (+bias on split 0); 5 = store partial[z]
template <int EPI>
__global__ __launch_bounds__(256) void gemm_bt_kernel(
    const bf16_t* __restrict__ A, const bf16_t* __restrict__ Bt,
    bf16_t* __restrict__ outb, float* __restrict__ outf,
    const float* __restrict__ bias, int M, int Nst, int K, int col0) {
  int bn, bm; remap_block(bn, bm);
  const int kz = blockIdx.z, KS = gridDim.z;
  const int Kc = K / KS;
  const int kbeg = kz * Kc, kend = kbeg + Kc;
  const int tid = threadIdx.x, wid = tid >> 6, lane = tid & 63;
  const int wm = wid >> 1, wn = wid & 1;
  const int l15 = lane & 15, l4 = lane >> 4;

  __shared__ __align__(16) bf16_t As[128 * 32];
  __shared__ __align__(16) bf16_t Bs[128 * 32];

  f32x4 acc[4][4] = {};

  const bf16_t* Ablk = A  + (size_t)(bm * 128) * K;
  const bf16_t* Bblk = Bt + (size_t)(bn * 128) * K;
  const int srow = lane >> 2;
  const int skof = (lane & 3) * 8;

  for (int k0 = kbeg; k0 < kend; k0 += 32) {
#pragma unroll
    for (int c = 0; c < 2; ++c) {
      int chunk = wid * 2 + c;
      int row = chunk * 16 + srow;
      gload_lds16(Ablk + (size_t)row * K + k0 + skof, As + chunk * 512);
      gload_lds16(Bblk + (size_t)row * K + k0 + skof, Bs + chunk * 512);
    }
    __syncthreads();

    bf16x8 af[4], bfv[4];
#pragma unroll
    for (int i = 0; i < 4; ++i)
      af[i] = *(const bf16x8*)(As + (wm * 64 + i * 16 + l15) * 32 + l4 * 8);
#pragma unroll
    for (int j = 0; j < 4; ++j)
      bfv[j] = *(const bf16x8*)(Bs + (wn * 64 + j * 16 + l15) * 32 + l4 * 8);
#pragma unroll
    for (int i = 0; i < 4; ++i)
#pragma unroll
      for (int j = 0; j < 4; ++j)
        acc[i][j] = __builtin_amdgcn_mfma_f32_16x16x32_bf16(af[i], bfv[j], acc[i][j], 0, 0, 0);
    __syncthreads();
  }

  const int row_base = bm * 128 + wm * 64;
  const int col_base = col0 + bn * 128 + wn * 64 + l15;
#pragma unroll
  for (int i = 0; i < 4; ++i) {
#pragma unroll
    for (int j = 0; j < 4; ++j) {
      int col = col_base + j * 16;
#pragma unroll
      for (int r = 0; r < 4; ++r) {
        int row = row_base + i * 16 + l4 * 4 + r;
        float val = acc[i][j][r];
        if (EPI == 5) {
          outf[(size_t)kz * 4194304 + (size_t)row * Nst + col] = val;
        } else {
          if (EPI == 3 && kz == 0) val += bias[col];
          atomicAdd(&outf[(size_t)row * Nst + col], val);
        }
      }
    }
  }
}

// ------- 256x256 8-wave GEMM, BK=64, 8-phase schedule, race-free stage map -------
// EPI: 2 = +bias,gelu,bf16; 4 = f32; 5 = QKV split
template <int EPI>
__global__ __launch_bounds__(512, 2) void gemm256_kernel(
    const bf16_t* __restrict__ A, const bf16_t* __restrict__ Bt,
    bf16_t* __restrict__ outb, float* __restrict__ outf,
    const float* __restrict__ bias, int M, int Nst, int K, int col0) {
  int bn, bm; remap_block(bn, bm);
  const int tid = threadIdx.x, wid = tid >> 6, lane = tid & 63;
  const int wm = wid >> 2, wn = wid & 3;          // 2 x 4 waves
  const int l15 = lane & 15, l4 = lane >> 4;

  __shared__ __align__(16) bf16_t smem[65536];

  f32x4 acc[8][4] = {};

  const bf16_t* Ab = A  + (size_t)(bm * 256) * K;
  const bf16_t* Bb = Bt + (size_t)(bn * 256) * K;
  const int NT = K >> 6;

  const int srow = tid >> 3;
  const int sx8  = tid & 7;
  const int xrd  = l15 & 7;

  auto stage_rows = [&](int t, int mat, int R) {
    const bf16_t* g = mat ? Bb : Ab;
    bf16_t* l = smem + (t & 1) * 32768 + mat * 16384 + R * 64;
    int row = R + srow;
    int gs  = sx8 ^ (row & 7);
    gload_lds16(g + (size_t)row * K + t * 64 + gs * 8, l + wid * 512);
  };
  auto stA_SP0 = [&](int t) { stage_rows(t, 0, 0);   stage_rows(t, 0, 128); };
  auto stA_SP1 = [&](int t) { stage_rows(t, 0, 64);  stage_rows(t, 0, 192); };
  auto stB_H0  = [&](int t) { stage_rows(t, 1, 0);   stage_rows(t, 1, 64);  };
  auto stB_H1  = [&](int t) { stage_rows(t, 1, 128); stage_rows(t, 1, 192); };

  stA_SP0(0); stB_H0(0); stA_SP1(0); stB_H1(0);
  stA_SP0(1); stB_H0(1); stA_SP1(1);
  asm volatile("s_waitcnt vmcnt(6)" ::: "memory");
  __builtin_amdgcn_s_barrier();

  bf16x8 af[4][2], bfr[4][2];

  auto rdB = [&](const bf16_t* sB, int nh) {
#pragma unroll
    for (int n = 0; n < 2; ++n)
#pragma unroll
      for (int ks = 0; ks < 2; ++ks)
        bfr[nh * 2 + n][ks] = *(const bf16x8*)(sB + (wn * 64 + (nh * 2 + n) * 16 + l15) * 64
                                                  + ((ks * 4 + l4) ^ xrd) * 8);
  };
  auto rdA = [&](const bf16_t* sA, int mh) {
#pragma unroll
    for (int m = 0; m < 4; ++m)
#pragma unroll
      for (int ks = 0; ks < 2; ++ks)
        af[m][ks] = *(const bf16x8*)(sA + (wm * 128 + mh * 64 + m * 16 + l15) * 64
                                        + ((ks * 4 + l4) ^ xrd) * 8);
  };
  auto mma = [&](int mh, int nh) {
    asm volatile("s_waitcnt lgkmcnt(0)" ::: "memory");
    __builtin_amdgcn_sched_barrier(0);
    __builtin_amdgcn_s_setprio(1);
#pragma unroll
    for (int m = 0; m < 4; ++m)
#pragma unroll
      for (int n = 0; n < 2; ++n)
#pragma unroll
        for (int ks = 0; ks < 2; ++ks)
          acc[mh * 4 + m][nh * 2 + n] = __builtin_amdgcn_mfma_f32_16x16x32_bf16(
              af[m][ks], bfr[nh * 2 + n][ks], acc[mh * 4 + m][nh * 2 + n], 0, 0, 0);
    __builtin_amdgcn_s_setprio(0);
  };

  const int NI = NT >> 1;
  for (int it = 0; it < NI; ++it) {
    const int T0 = 2 * it, T1 = 2 * it + 1;
    const bool pre = (it + 1 < NI);
    const bf16_t* sA0 = smem;
    const bf16_t* sB0 = smem + 16384;
    const bf16_t* sA1 = smem + 32768;
    const bf16_t* sB1 = smem + 49152;

    rdB(sB0, 0); rdA(sA0, 0);
    stB_H1(T1);
    asm volatile("s_waitcnt lgkmcnt(8)" ::: "memory");
    __builtin_amdgcn_s_barrier();
    mma(0, 0);
    __builtin_amdgcn_s_barrier();
    rdB(sB0, 1);
    if (pre) stA_SP0(T0 + 2);
    __builtin_amdgcn_s_barrier();
    mma(0, 1);
    __builtin_amdgcn_s_barrier();
    rdA(sA0, 1);
    if (pre) stB_H0(T0 + 2);
    __builtin_amdgcn_s_barrier();
    mma(1, 0);
    __builtin_amdgcn_s_barrier();
    if (pre) stA_SP1(T0 + 2);
    __builtin_amdgcn_s_barrier();
    mma(1, 1);
    if (pre) { asm volatile("s_waitcnt vmcnt(6)" ::: "memory"); }
    else     { asm volatile("s_waitcnt vmcnt(0)" ::: "memory"); }
    __builtin_amdgcn_s_barrier();

    rdB(sB1, 0); rdA(sA1, 0);
    if (pre) stB_H1(T0 + 2);
    asm volatile("s_waitcnt lgkmcnt(8)" ::: "memory");
    __builtin_amdgcn_s_barrier();
    mma(0, 0);
    __builtin_amdgcn_s_barrier();
    rdB(sB1, 1);
    if (pre) stA_SP0(T1 + 2);
    __builtin_amdgcn_s_barrier();
    mma(0, 1);
    __builtin_amdgcn_s_barrier();
    rdA(sA1, 1);
    if (pre) stB_H0(T1 + 2);
    __builtin_amdgcn_s_barrier();
    mma(1, 0);
    __builtin_amdgcn_s_barrier();
    if (pre) stA_SP1(T1 + 2);
    __builtin_amdgcn_s_barrier();
    mma(1, 1);
    if (pre) { asm volatile("s_waitcnt vmcnt(6)" ::: "memory"); }
    __builtin_amdgcn_s_barrier();
  }

  const int row_base = bm * 256 + wm * 128;
#pragma unroll
  for (int m = 0; m < 8; ++m) {
#pragma unroll
    for (int n = 0; n < 4; ++n) {
      int colg = bn * 256 + wn * 64 + n * 16 + l15;
#pragma unroll
      for (int r = 0; r < 4; ++r) {
        int row = row_base + m * 16 + l4 * 4 + r;
        float val = acc[m][n][r];
        if (EPI == 4) {
          outf[(size_t)row * Nst + col0 + colg] = val;
        } else if (EPI == 2) {
          int col = col0 + colg;
          float v2 = val + bias[col];
          v2 = 0.5f * v2 * (1.0f + erff(v2 * 0.7071067811865475f));
          outb[(size_t)row * Nst + col] = (bf16_t)v2;
        } else {
          int buf = colg >> 10;
          int lc  = colg & 1023;
          (outb + (size_t)buf * 4194304)[(size_t)row * 1024 + lc] = (bf16_t)val;
        }
      }
    }
  }
}

// ---------------- flash attention (causal), 1 block = (b, h, 128 q-rows), 8 waves ----------------
// KVBLK=128: stage K/V for TWO 64-tiles per sync round (halves barrier+staging rounds).
// Ks[128][72]; V^T rotated: V[j][d] at Vs[d*136 + ((j + (d&56)) & 127)] (<=2-way banks).
// softmax in log2 domain (exp2 = native v_exp_f32).
__global__ __launch_bounds__(512) void attn_kernel(
    const bf16_t* __restrict__ q, const bf16_t* __restrict__ k,
    const bf16_t* __restrict__ v, bf16_t* __restrict__ y) {
  int bid = blockIdx.x;
  int qt = bid & 7;               // L/128 = 8
  int h  = (bid >> 3) & (H_ - 1);
  int b  = bid >> 7;
  int tid = threadIdx.x, wid = tid >> 6, lane = tid & 63;
  int l15 = lane & 15, l4 = lane >> 4;

  __shared__ __align__(16) bf16_t Ks[128 * 72];
  __shared__ __align__(16) bf16_t Vs[64 * 136];
  __shared__ __align__(16) bf16_t Ps[8][16 * 72];

  const int qrow0 = qt * 128 + wid * 16;
  const int qmax  = qrow0 + 15;
  const size_t bh = ((size_t)b * L_ * H_ + h) * HD_;
  const float SCL = 0.125f * 1.44269504f;   // (1/sqrt(64)) * log2(e)

  bf16x8 qf[2];
#pragma unroll
  for (int c = 0; c < 2; ++c)
    qf[c] = *(const bf16x8*)(q + bh + (size_t)(qrow0 + l15) * (H_ * HD_) + c * 32 + l4 * 8);

  float m_r[4] = {-INFINITY, -INFINITY, -INFINITY, -INFINITY};
  float l_r[4] = {0.f, 0.f, 0.f, 0.f};
  f32x4 oacc[4] = {};

  for (int st = 0; st <= qt; ++st) {
    __syncthreads();
    int kbase0 = st * 128;
    // stage 128 rows of K and V (1024 bf16x8 chunks, 2 per thread)
#pragma unroll
    for (int c = 0; c < 2; ++c) {
      int seg = c * 512 + tid;
      int j = seg >> 3;                      // 0..127
      int dof = (seg & 7) * 8;               // 0..56
      const size_t src = bh + (size_t)(kbase0 + j) * (H_ * HD_) + dof;
      *(bf16x8*)(Ks + j * 72 + dof) = *(const bf16x8*)(k + src);
      bf16x8 vv = *(const bf16x8*)(v + src);
      int colb = (j + dof) & 127;
#pragma unroll
      for (int jj = 0; jj < 8; ++jj) Vs[(dof + jj) * 136 + colb] = vv[jj];
    }
    __syncthreads();

#pragma unroll
    for (int half = 0; half < 2; ++half) {
      int kbase = kbase0 + half * 64;
      if (kbase > qmax) continue;

      f32x4 sacc[4] = {};
#pragma unroll
      for (int c = 0; c < 2; ++c) {
#pragma unroll
        for (int t = 0; t < 4; ++t) {
          bf16x8 kf = *(const bf16x8*)(Ks + (half * 64 + t * 16 + l15) * 72 + c * 32 + l4 * 8);
          sacc[t] = __builtin_amdgcn_mfma_f32_16x16x32_bf16(qf[c], kf, sacc[t], 0, 0, 0);
        }
      }

      float tmax[4] = {-INFINITY, -INFINITY, -INFINITY, -INFINITY};
#pragma unroll
      for (int t = 0; t < 4; ++t) {
#pragma unroll
        for (int r = 0; r < 4; ++r) {
          float sv = sacc[t][r] * SCL;
          int kj = kbase + t * 16 + l15;
          int qi = qrow0 + l4 * 4 + r;
          if (kj > qi) sv = -INFINITY;
          sacc[t][r] = sv;
          tmax[r] = fmaxf(tmax[r], sv);
        }
      }
#pragma unroll
      for (int r = 0; r < 4; ++r) {
#pragma unroll
        for (int md = 1; md < 16; md <<= 1)
          tmax[r] = fmaxf(tmax[r], __shfl_xor(tmax[r], md));
      }
      float alpha[4], tsum[4];
#pragma unroll
      for (int r = 0; r < 4; ++r) {
        float mn = fmaxf(m_r[r], tmax[r]);
        alpha[r] = exp2f(m_r[r] - mn);
        m_r[r] = mn;
        tsum[r] = 0.f;
      }
#pragma unroll
      for (int t = 0; t < 4; ++t) {
#pragma unroll
        for (int r = 0; r < 4; ++r) {
          float p = exp2f(sacc[t][r] - m_r[r]);
          tsum[r] += p;
          Ps[wid][(l4 * 4 + r) * 72 + t * 16 + l15] = (bf16_t)p;
        }
      }
#pragma unroll
      for (int r = 0; r < 4; ++r) {
#pragma unroll
        for (int md = 1; md < 16; md <<= 1)
          tsum[r] += __shfl_xor(tsum[r], md);
        l_r[r] = l_r[r] * alpha[r] + tsum[r];
      }
#pragma unroll
      for (int t = 0; t < 4; ++t)
#pragma unroll
        for (int r = 0; r < 4; ++r)
          oacc[t][r] *= alpha[r];

#pragma unroll
      for (int c = 0; c < 2; ++c) {
        bf16x8 pf = *(const bf16x8*)(&Ps[wid][l15 * 72 + c * 32 + l4 * 8]);
#pragma unroll
        for (int t = 0; t < 4; ++t) {
          int d = t * 16 + l15;
          int jb = half * 64 + c * 32 + l4 * 8;
          bf16x8 vf = *(const bf16x8*)(Vs + d * 136 + ((jb + (d & 56)) & 127));
          oacc[t] = __builtin_amdgcn_mfma_f32_16x16x32_bf16(pf, vf, oacc[t], 0, 0, 0);
        }
      }
    }
  }

#pragma unroll
  for (int t = 0; t < 4; ++t) {
#pragma unroll
    for (int r = 0; r < 4; ++r) {
      int row = qrow0 + l4 * 4 + r;
      int d = t * 16 + l15;
      y[bh + (size_t)row * (H_ * HD_) + d] = (bf16_t)(oacc[t][r] / l_r[r]);
    }
  }
}

// ---------------- host launcher ----------------
extern "C" void kernel_launch(void* const* d_in, const int* in_sizes, int n_in,
                              void* d_out, int out_size, void* d_ws, size_t ws_size,
                              hipStream_t stream) {
  (void)in_sizes; (void)n_in; (void)out_size;
  const int*   idx   = (const int*)d_in[0];
  const float* emb   = (const float*)d_in[1];
  const float* ln1_s = (const float*)d_in[2];
  const float* ln1_b = (const float*)d_in[3];
  const float* wq    = (const float*)d_in[4];
  const float* wk    = (const float*)d_in[5];
  const float* wv    = (const float*)d_in[6];
  const float* wo    = (const float*)d_in[7];
  const float* ln2_s = (const float*)d_in[8];
  const float* ln2_b = (const float*)d_in[9];
  const float* w1    = (const float*)d_in[10];
  const float* b1    = (const float*)d_in[11];
  const float* w2    = (const float*)d_in[12];
  const float* b2    = (const float*)d_in[13];
  const float* lnf_s = (const float*)d_in[14];
  const float* lnf_b = (const float*)d_in[15];
  const float* headw = (const float*)d_in[16];
  float* out = (float*)d_out;

  char* ws = (char*)d_ws;
  const size_t XO  = 0;
  const size_t HBO = XO  + 16777216;
  const size_t QBO = HBO + 8388608;
  const size_t KBO = QBO + 8388608;
  const size_t VBO = KBO + 8388608;
  const size_t YBO = VBO + 8388608;
  const size_t GBO = QBO;
  const size_t WTO = YBO + 8388608;
  const size_t LBYTES = 25165824;
  const size_t LELEMS = LBYTES / 2;
  const size_t PREB = (size_t)NL_ * LBYTES;
  const size_t WOPO = WTO + PREB;
  const size_t F2PO = WOPO + 33554432;
  const size_t HWTO = F2PO + 67108864;
  const size_t NEED = HWTO + (size_t)V_ * D_ * 2;
  const bool big = ws_size >= NEED;
  const bool prepass = big || (ws_size >= WTO + PREB);

  float*  X   = (float*)(ws + XO);
  bf16_t* Hb  = (bf16_t*)(ws + HBO);
  bf16_t* Qb  = (bf16_t*)(ws + QBO);
  bf16_t* Kb  = (bf16_t*)(ws + KBO);
  bf16_t* Vb  = (bf16_t*)(ws + VBO);
  bf16_t* Yb  = (bf16_t*)(ws + YBO);
  bf16_t* Gb  = (bf16_t*)(ws + GBO);
  bf16_t* Wbase = (bf16_t*)(ws + WTO);
  float*  woP = (float*)(ws + WOPO);
  float*  f2P = (float*)(ws + F2PO);

  const int M = B_ * L_;
  const dim3 tb16(16, 16);

  embed_kernel<<<M, 256, 0, stream>>>(idx, emb, X);

  if (prepass)
    transpose_all<<<NL_ * 3072, tb16, 0, stream>>>(wq, wk, wv, wo, w1, w2, 0, Wbase, LELEMS);

  for (int l = 0; l < NL_; ++l) {
    bf16_t* wl = prepass ? (Wbase + (size_t)l * LELEMS) : Wbase;
    bf16_t* qkvT = wl;
    bf16_t* woT  = wl + 3145728;
    bf16_t* w1T  = wl + 4194304;
    bf16_t* w2T  = wl + 8388608;

    if (big && l > 0) {
      ln_red_kernel<4><<<M, 256, 0, stream>>>(X, f2P, b2 + (size_t)(l - 1) * D_,
                                              ln1_s + (size_t)l * D_, ln1_b + (size_t)l * D_, Hb);
    } else {
      ln_kernel<<<M, 256, 0, stream>>>(X, ln1_s + (size_t)l * D_, ln1_b + (size_t)l * D_, Hb);
    }

    if (!prepass)
      transpose_all<<<3072, tb16, 0, stream>>>(wq, wk, wv, wo, w1, w2, l, Wbase, 0);

    gemm256_kernel<5><<<dim3(3*D_/256, M/256), 512, 0, stream>>>(Hb, qkvT, Qb, nullptr, nullptr, M, D_, D_, 0);

    attn_kernel<<<B_ * H_ * (L_/128), 512, 0, stream>>>(Qb, Kb, Vb, Yb);

    if (big) {
      gemm_bt_kernel<5><<<dim3(D_/128, M/128, 2), 256, 0, stream>>>(Yb, woT, nullptr, woP, nullptr, M, D_, D_, 0);
      ln_red_kernel<2><<<M, 256, 0, stream>>>(X, woP, nullptr,
                                              ln2_s + (size_t)l * D_, ln2_b + (size_t)l * D_, Hb);
    } else {
      gemm_bt_kernel<1><<<dim3(D_/128, M/128, 2), 256, 0, stream>>>(Yb, woT, nullptr, X, nullptr, M, D_, D_, 0);
      ln_kernel<<<M, 256, 0, stream>>>(X, ln2_s + (size_t)l * D_, ln2_b + (size_t)l * D_, Hb);
    }

    gemm256_kernel<2><<<dim3(FF_/256, M/256), 512, 0, stream>>>(Hb, w1T, Gb, nullptr, b1 + (size_t)l * FF_, M, FF_, D_, 0);

    if (big) {
      gemm_bt_kernel<5><<<dim3(D_/128, M/128, 4), 256, 0, stream>>>(Gb, w2T, nullptr, f2P, nullptr, M, D_, FF_, 0);
    } else {
      gemm_bt_kernel<3><<<dim3(D_/128, M/128, 4), 256, 0, stream>>>(Gb, w2T, nullptr, X, b2 + (size_t)l * D_, M, D_, FF_, 0);
    }
  }

  if (big) {
    ln_red_kernel<4><<<M, 256, 0, stream>>>(X, f2P, b2 + (size_t)(NL_ - 1) * D_, lnf_s, lnf_b, Hb);
    bf16_t* HWT = (bf16_t*)(ws + HWTO);
    transpose64_k<<<dim3(V_/64, D_/64), tb16, 0, stream>>>(headw, 0, HWT, D_, V_);
    gemm256_kernel<4><<<dim3(V_/256, M/256), 512, 0, stream>>>(Hb, HWT, nullptr, out, nullptr, M, V_, D_, 0);
  } else {
    ln_kernel<<<M, 256, 0, stream>>>(X, lnf_s, lnf_b, Hb);
    bf16_t* WT = (bf16_t*)(ws + WTO);
    size_t avail = (ws_size > WTO) ? (ws_size - WTO) : 0;
    long long maxcols = (long long)(avail / ((size_t)D_ * 2));
    int chunk = (int)((maxcols / 256) * 256);
    if (chunk > V_) chunk = V_;
    if (chunk < 256) chunk = 256;
    for (int n0 = 0; n0 < V_; n0 += chunk) {
      int nc = (V_ - n0 < chunk) ? (V_ - n0) : chunk;
      transpose64_k<<<dim3(nc/64, D_/64), tb16, 0, stream>>>(headw, (size_t)n0, WT, D_, V_);
      gemm256_kernel<4><<<dim3(nc/256, M/256), 512, 0, stream>>>(Hb, WT, nullptr, out, nullptr, M, V_, D_, n0);
    }
  }
}